// Round 5
// baseline (406.397 us; speedup 1.0000x reference)
//
#include <hip/hip_runtime.h>
#include <hip/hip_cooperative_groups.h>
#include <math.h>

namespace cg = cooperative_groups;

#define NG 256     // NUM_GRAPHS
// bucket = target >> 8 (256 nodes/bucket, NB<=512); src packs in 17 bits (N <= 131072)

// fp8-e4m3 staging scales (powers of 2: exactly invertible)
#define S1F 16.0f
#define IS1F 0.0625f
#define S2F 64.0f
#define IS2F 0.015625f

typedef __attribute__((ext_vector_type(2))) float f32x2;

__device__ __forceinline__ unsigned enc4(float f0, float f1, float f2, float f3) {
    int r = __builtin_amdgcn_cvt_pk_fp8_f32(f0, f1, 0, false);
    r = __builtin_amdgcn_cvt_pk_fp8_f32(f2, f3, r, true);
    return (unsigned)r;
}
// accumulate 8 fp8 feats (one uint2) into 4 packed f32x2 accumulators
__device__ __forceinline__ void acc8p(uint2 v, f32x2 (&a)[4]) {
    a[0] += __builtin_amdgcn_cvt_pk_f32_fp8((int)v.x, false);
    a[1] += __builtin_amdgcn_cvt_pk_f32_fp8((int)v.x, true);
    a[2] += __builtin_amdgcn_cvt_pk_f32_fp8((int)v.y, false);
    a[3] += __builtin_amdgcn_cvt_pk_f32_fp8((int)v.y, true);
}

// ---------------------------------------------------------------------------
// ONE cooperative kernel for the whole CSR build:
//   P0 bounds | P1 bucket hist + range reservation (offsets in LDS)
//   gsync | P2 redundant per-block scan of btot -> bases (LDS)
//   P3 scatter pairs | gsync | P4 per-bucket CSR (rowptr, dinv, adj)
// Replaces 5 dispatches + 4 launch gaps + global blockOff/bucketBase traffic.
__global__ __launch_bounds__(256) void build_coop_kernel(
        const int* __restrict__ ei, const int* __restrict__ bat,
        int* __restrict__ btot, int* __restrict__ pairs,
        int* __restrict__ rowptr, int* __restrict__ adj,
        float* __restrict__ dinv, int* __restrict__ starts,
        int N, int E, int NB) {
    __shared__ int A[513];     // bucket base (exclusive scan), A[NB] = total
    __shared__ int Boff[512];  // this block's reserved offset per bucket
    __shared__ int C[512];     // hist counts -> scan ping -> scatter cursors -> csr scan
    __shared__ int D[512];     // scan pong -> csr hist/cursor
    const int b = blockIdx.x, t = threadIdx.x;
    cg::grid_group grid = cg::this_grid();

    // ---- P0: segment bounds from sorted batch ----
    {
        int i = b * 256 + t;
        if (i < N) {
            int bb = bat[i];
            int bp = (i == 0) ? -1 : bat[i - 1];
            for (int g = bp + 1; g <= bb; g++) starts[g] = i;
            if (i == N - 1)
                for (int g = bb + 1; g <= NG; g++) starts[g] = N;
        }
    }

    // ---- P1: per-block histogram of edge targets into NB buckets ----
    C[t] = 0; C[t + 256] = 0;
    __syncthreads();
    const int chunk = (((E + NB - 1) / NB) + 3) & ~3;   // 4-aligned per-block chunk
    const int beg = b * chunk;
    const int end = min(beg + chunk, E);
    const int* col = ei + E;
    if ((E & 3) == 0) {
        for (int e = beg + t * 4; e + 3 < end; e += 1024) {
            int4 c = *(const int4*)(col + e);
            atomicAdd(&C[c.x >> 8], 1);
            atomicAdd(&C[c.y >> 8], 1);
            atomicAdd(&C[c.z >> 8], 1);
            atomicAdd(&C[c.w >> 8], 1);
        }
    } else {
        for (int e = beg + t; e < end; e += 256)
            atomicAdd(&C[col[e] >> 8], 1);
    }
    __syncthreads();
    if (t < NB)       Boff[t]       = atomicAdd(&btot[t], C[t]);
    if (t + 256 < NB) Boff[t + 256] = atomicAdd(&btot[t + 256], C[t + 256]);

    grid.sync();   // all blocks' reservations in btot

    // ---- P2: redundant per-block exclusive scan of btot -> A (bases) ----
    const int v0 = (t < NB) ? btot[t] : 0;
    const int v1 = (t + 256 < NB) ? btot[t + 256] : 0;
    C[t] = v0; C[t + 256] = v1;
    __syncthreads();
    {
        int* src = C; int* dst = D;
        for (int off = 1; off < 512; off <<= 1) {
            int a0 = src[t] + ((t >= off) ? src[t - off] : 0);
            int a1 = src[t + 256] + src[t + 256 - off];   // t+256 >= off always (off<=256)
            dst[t] = a0; dst[t + 256] = a1;
            __syncthreads();
            int* tm = src; src = dst; dst = tm;
        }
        const int inc0 = src[t], inc1 = src[t + 256], tot = src[511];
        __syncthreads();          // everyone done reading ping-pong
        A[t] = inc0 - v0;         // exclusive base
        A[t + 256] = inc1 - v1;
        if (t == 0) A[NB] = tot;  // (equals the formula value when NB < 512)
    }
    // scatter cursors: base + this block's reserved offset
    C[t] = A[t] + Boff[t];
    C[t + 256] = A[t + 256] + Boff[t + 256];
    __syncthreads();

    // ---- P3: scatter packed (local_tgt<<17 | src) pairs ----
    if ((E & 3) == 0) {
        for (int e = beg + t * 4; e + 3 < end; e += 1024) {
            int4 s = *(const int4*)(ei + e);
            int4 tg = *(const int4*)(col + e);
            int p0 = atomicAdd(&C[tg.x >> 8], 1);
            pairs[p0] = (int)(((unsigned)(tg.x & 255) << 17) | (unsigned)s.x);
            int p1 = atomicAdd(&C[tg.y >> 8], 1);
            pairs[p1] = (int)(((unsigned)(tg.y & 255) << 17) | (unsigned)s.y);
            int p2 = atomicAdd(&C[tg.z >> 8], 1);
            pairs[p2] = (int)(((unsigned)(tg.z & 255) << 17) | (unsigned)s.z);
            int p3 = atomicAdd(&C[tg.w >> 8], 1);
            pairs[p3] = (int)(((unsigned)(tg.w & 255) << 17) | (unsigned)s.w);
        }
    } else {
        for (int e = beg + t; e < end; e += 256) {
            int src = ei[e];
            int tgt = col[e];
            int pos = atomicAdd(&C[tgt >> 8], 1);
            pairs[pos] = (int)(((unsigned)(tgt & 255) << 17) | (unsigned)src);
        }
    }

    grid.sync();   // all pairs written

    // ---- P4: per-bucket CSR (this block owns bucket b) ----
    const int base = A[b];
    const int bend = A[b + 1];
    D[t] = 0;
    __syncthreads();
    for (int i = base + t; i < bend; i += 256)
        atomicAdd(&D[(unsigned)pairs[i] >> 17], 1);
    __syncthreads();
    const int hv = D[t];
    C[t] = hv;
    __syncthreads();
    for (int o = 1; o < 256; o <<= 1) {
        int u = (t >= o) ? C[t - o] : 0;
        __syncthreads();
        C[t] += u;
        __syncthreads();
    }
    const int ex = C[t] - hv;
    const int node = (b << 8) + t;
    if (node < N) {
        rowptr[node] = base + ex;
        dinv[node] = rsqrtf((float)hv + 1.0f);
    }
    D[t] = base + ex;   // per-node cursor
    __syncthreads();
    for (int i = base + t; i < bend; i += 256) {
        unsigned p = (unsigned)pairs[i];
        int pos = atomicAdd(&D[p >> 17], 1);
        adj[pos] = (int)(p & 0x1FFFFu);
    }
    if (b == 0 && t == 0) rowptr[N] = E;
}

// ---------------------------------------------------------------------------
// hs1[i][f] = fp8( (x[i]@W1)[f] * dinv[i] * S1 )   (32 feats -> 32 B rows)
// Row N (one past the end) is written as all-zero: the gathers clamp masked
// edge slots to index N so the loaded payload is exactly 0.0 (no VALU masking).
__global__ __launch_bounds__(256) void hs1_kernel(
        const float* __restrict__ x, const float* __restrict__ W,
        const float* __restrict__ dinv, unsigned* __restrict__ hs, int N) {
    __shared__ float Ws[32 * 32];
    __shared__ float tmp[8][32];
    for (int t = threadIdx.x; t < 1024; t += blockDim.x) Ws[t] = W[t];
    __syncthreads();
    const int tid = threadIdx.x;
    const int node = blockIdx.x * 8 + (tid >> 5);
    const int n = tid >> 5, f = tid & 31;
    if (node < N) {
        const float* xr = x + (size_t)node * 32;
        float acc = 0.f;
#pragma unroll
        for (int k = 0; k < 32; k++) acc += xr[k] * Ws[k * 32 + f];
        tmp[n][f] = acc * dinv[node] * S1F;
        if (f < 8)   // same-wave producer/consumer
            hs[(size_t)node * 8 + f] = enc4(tmp[n][4 * f], tmp[n][4 * f + 1],
                                            tmp[n][4 * f + 2], tmp[n][4 * f + 3]);
    } else if (node == N) {
        if (f < 8) hs[(size_t)N * 8 + f] = 0u;    // zero row
    }
}

// ---------------------------------------------------------------------------
// gather layer 1: 2 nodes per 32-lane group (16 nodes/block). Uniform masked
// 32-edge loop per node, both nodes' loads interleaved -> 8 adj + 8 row loads
// in flight per lane. Masked slots clamp the adj index to N (zero row).
__global__ __launch_bounds__(256) void gather1_kernel(
        const int* __restrict__ rowptr, const int* __restrict__ adj,
        const uint2* __restrict__ hs1q, const float* __restrict__ dinv,
        const float* __restrict__ b1, const float* __restrict__ W2,
        unsigned* __restrict__ hs2out, int N) {
    __shared__ float W2s[32 * 24];
    __shared__ float b1s[32];
    __shared__ float h1row[16][32];
    __shared__ float hs2t[16][32];
    const int tid = threadIdx.x;
    for (int t = tid; t < 768; t += 256) W2s[t] = W2[t];
    if (tid < 32) b1s[tid] = b1[tid];
    if (blockIdx.x == 0 && tid < 8) hs2out[(size_t)N * 8 + tid] = 0u;  // zero row for gather2

    const int g = tid >> 5;          // group 0..7
    const int l = tid & 31;
    const int f8 = l & 3;            // feature octet
    const int e8 = l >> 2;           // edge slot 0..7
    const int n0 = (blockIdx.x * 8 + g) * 2;
    const int n1 = n0 + 1;
    const bool val0 = n0 < N;
    const bool val1 = n1 < N;

    int beg0 = 0, cnt0 = 0, beg1 = 0, cnt1 = 0;
    if (val0) {
        int2 rp = *(const int2*)(rowptr + n0);       // n0 even -> 8B aligned
        beg0 = rp.x; cnt0 = rp.y - rp.x;
        if (val1) { int e2 = rowptr[n0 + 2]; beg1 = rp.y; cnt1 = e2 - rp.y; }
    }
    const int* ap0 = adj + beg0;
    const int* ap1 = adj + beg1;
    f32x2 a0[4], a1[4];
#pragma unroll
    for (int k = 0; k < 4; k++) { a0[k][0] = 0.f; a0[k][1] = 0.f; a1[k][0] = 0.f; a1[k][1] = 0.f; }

    const int jmax = max(cnt0, cnt1);
    for (int j = 0; j < jmax; j += 32) {
        const int i0 = j + e8, i1 = j + 8 + e8, i2 = j + 16 + e8, i3 = j + 24 + e8;
        // adj loads, both nodes (reads past row end land in valid workspace;
        // index clamped to zero row N)
        int sA0 = ap0[i0], sA1 = ap0[i1], sA2 = ap0[i2], sA3 = ap0[i3];
        int sB0 = ap1[i0], sB1 = ap1[i1], sB2 = ap1[i2], sB3 = ap1[i3];
        if (i0 >= cnt0) sA0 = N; if (i1 >= cnt0) sA1 = N;
        if (i2 >= cnt0) sA2 = N; if (i3 >= cnt0) sA3 = N;
        if (i0 >= cnt1) sB0 = N; if (i1 >= cnt1) sB1 = N;
        if (i2 >= cnt1) sB2 = N; if (i3 >= cnt1) sB3 = N;
        // row loads, both nodes (row N = zeros -> exact +0.0 adds)
        uint2 vA0 = hs1q[(size_t)sA0 * 4 + f8];
        uint2 vA1 = hs1q[(size_t)sA1 * 4 + f8];
        uint2 vA2 = hs1q[(size_t)sA2 * 4 + f8];
        uint2 vA3 = hs1q[(size_t)sA3 * 4 + f8];
        uint2 vB0 = hs1q[(size_t)sB0 * 4 + f8];
        uint2 vB1 = hs1q[(size_t)sB1 * 4 + f8];
        uint2 vB2 = hs1q[(size_t)sB2 * 4 + f8];
        uint2 vB3 = hs1q[(size_t)sB3 * 4 + f8];
        acc8p(vA0, a0); acc8p(vA1, a0); acc8p(vA2, a0); acc8p(vA3, a0);
        acc8p(vB0, a1); acc8p(vB1, a1); acc8p(vB2, a1); acc8p(vB3, a1);
    }
#pragma unroll
    for (int k = 0; k < 4; k++) {                // fold 8 edge slots (lane bits 2,3,4)
        float x0 = a0[k][0], x1 = a0[k][1], y0 = a1[k][0], y1 = a1[k][1];
        x0 += __shfl_xor(x0, 4); x0 += __shfl_xor(x0, 8); x0 += __shfl_xor(x0, 16);
        x1 += __shfl_xor(x1, 4); x1 += __shfl_xor(x1, 8); x1 += __shfl_xor(x1, 16);
        y0 += __shfl_xor(y0, 4); y0 += __shfl_xor(y0, 8); y0 += __shfl_xor(y0, 16);
        y1 += __shfl_xor(y1, 4); y1 += __shfl_xor(y1, 8); y1 += __shfl_xor(y1, 16);
        a0[k][0] = x0; a0[k][1] = x1; a1[k][0] = y0; a1[k][1] = y1;
    }

    __syncthreads();   // weight/bias staging visibility (all threads reach here)

    // finalize: lanes 0..3 do n0, lanes 4..7 do n1 (8 feats each)
    auto fin1 = [&](const f32x2 (&a)[4], int node, int row) {
        const int fq = l & 3;
        const float c = dinv[node] * IS1F;
        uint2 w = hs1q[(size_t)node * 4 + fq];           // self-loop term
        f32x2 s0 = __builtin_amdgcn_cvt_pk_f32_fp8((int)w.x, false);
        f32x2 s1 = __builtin_amdgcn_cvt_pk_f32_fp8((int)w.x, true);
        f32x2 s2 = __builtin_amdgcn_cvt_pk_f32_fp8((int)w.y, false);
        f32x2 s3 = __builtin_amdgcn_cvt_pk_f32_fp8((int)w.y, true);
        h1row[row][8 * fq + 0] = fmaxf(c * (a[0][0] + s0[0]) + b1s[8 * fq + 0], 0.f);
        h1row[row][8 * fq + 1] = fmaxf(c * (a[0][1] + s0[1]) + b1s[8 * fq + 1], 0.f);
        h1row[row][8 * fq + 2] = fmaxf(c * (a[1][0] + s1[0]) + b1s[8 * fq + 2], 0.f);
        h1row[row][8 * fq + 3] = fmaxf(c * (a[1][1] + s1[1]) + b1s[8 * fq + 3], 0.f);
        h1row[row][8 * fq + 4] = fmaxf(c * (a[2][0] + s2[0]) + b1s[8 * fq + 4], 0.f);
        h1row[row][8 * fq + 5] = fmaxf(c * (a[2][1] + s2[1]) + b1s[8 * fq + 5], 0.f);
        h1row[row][8 * fq + 6] = fmaxf(c * (a[3][0] + s3[0]) + b1s[8 * fq + 6], 0.f);
        h1row[row][8 * fq + 7] = fmaxf(c * (a[3][1] + s3[1]) + b1s[8 * fq + 7], 0.f);
    };
    if (l < 4) { if (val0) fin1(a0, n0, 2 * g); }
    else if (l < 8) { if (val1) fin1(a1, n1, 2 * g + 1); }

    // @W2 + fp8 stage, two serial passes (same-wave producer/consumer via LDS)
#pragma unroll
    for (int nn = 0; nn < 2; ++nn) {
        const int node = n0 + nn;
        if (node >= N) break;
        const int row = 2 * g + nn;
        const float sc = dinv[node] * S2F;
        float aa = 0.f;
        if (l < 24) {
#pragma unroll
            for (int k = 0; k < 32; k++) aa += h1row[row][k] * W2s[k * 24 + l];
        }
        hs2t[row][l] = (l < 24) ? aa * sc : 0.f;
        if (l < 8)
            hs2out[(size_t)node * 8 + l] = enc4(hs2t[row][4 * l], hs2t[row][4 * l + 1],
                                                hs2t[row][4 * l + 2], hs2t[row][4 * l + 3]);
    }
}

// gather layer 2: same 2-node structure; finalize writes h2 + fused node-MLP.
__global__ __launch_bounds__(256) void gather2_kernel(
        const int* __restrict__ rowptr, const int* __restrict__ adj,
        const uint2* __restrict__ hs2q, const float* __restrict__ dinv,
        const float* __restrict__ b2,
        const float* __restrict__ Wn1, const float* __restrict__ bn1,
        const float* __restrict__ Wn2, const float* __restrict__ bn2,
        float* __restrict__ h2out, float* __restrict__ vout, int N) {
    __shared__ float Wn1s[24 * 16];
    __shared__ float b2s[32], bn1s[16], Wn2s[16];
    __shared__ float h2row[16][32];
    const int tid = threadIdx.x;
    for (int t = tid; t < 384; t += 256) Wn1s[t] = Wn1[t];
    if (tid < 32) b2s[tid] = (tid < 24) ? b2[tid] : 0.f;
    if (tid < 16) { bn1s[tid] = bn1[tid]; Wn2s[tid] = Wn2[tid]; }

    const int g = tid >> 5;
    const int l = tid & 31;
    const int f8 = l & 3;
    const int e8 = l >> 2;
    const int n0 = (blockIdx.x * 8 + g) * 2;
    const int n1 = n0 + 1;
    const bool val0 = n0 < N;
    const bool val1 = n1 < N;

    int beg0 = 0, cnt0 = 0, beg1 = 0, cnt1 = 0;
    if (val0) {
        int2 rp = *(const int2*)(rowptr + n0);
        beg0 = rp.x; cnt0 = rp.y - rp.x;
        if (val1) { int e2 = rowptr[n0 + 2]; beg1 = rp.y; cnt1 = e2 - rp.y; }
    }
    const int* ap0 = adj + beg0;
    const int* ap1 = adj + beg1;
    f32x2 a0[4], a1[4];
#pragma unroll
    for (int k = 0; k < 4; k++) { a0[k][0] = 0.f; a0[k][1] = 0.f; a1[k][0] = 0.f; a1[k][1] = 0.f; }

    const int jmax = max(cnt0, cnt1);
    for (int j = 0; j < jmax; j += 32) {
        const int i0 = j + e8, i1 = j + 8 + e8, i2 = j + 16 + e8, i3 = j + 24 + e8;
        int sA0 = ap0[i0], sA1 = ap0[i1], sA2 = ap0[i2], sA3 = ap0[i3];
        int sB0 = ap1[i0], sB1 = ap1[i1], sB2 = ap1[i2], sB3 = ap1[i3];
        if (i0 >= cnt0) sA0 = N; if (i1 >= cnt0) sA1 = N;
        if (i2 >= cnt0) sA2 = N; if (i3 >= cnt0) sA3 = N;
        if (i0 >= cnt1) sB0 = N; if (i1 >= cnt1) sB1 = N;
        if (i2 >= cnt1) sB2 = N; if (i3 >= cnt1) sB3 = N;
        uint2 vA0 = hs2q[(size_t)sA0 * 4 + f8];
        uint2 vA1 = hs2q[(size_t)sA1 * 4 + f8];
        uint2 vA2 = hs2q[(size_t)sA2 * 4 + f8];
        uint2 vA3 = hs2q[(size_t)sA3 * 4 + f8];
        uint2 vB0 = hs2q[(size_t)sB0 * 4 + f8];
        uint2 vB1 = hs2q[(size_t)sB1 * 4 + f8];
        uint2 vB2 = hs2q[(size_t)sB2 * 4 + f8];
        uint2 vB3 = hs2q[(size_t)sB3 * 4 + f8];
        acc8p(vA0, a0); acc8p(vA1, a0); acc8p(vA2, a0); acc8p(vA3, a0);
        acc8p(vB0, a1); acc8p(vB1, a1); acc8p(vB2, a1); acc8p(vB3, a1);
    }
#pragma unroll
    for (int k = 0; k < 4; k++) {
        float x0 = a0[k][0], x1 = a0[k][1], y0 = a1[k][0], y1 = a1[k][1];
        x0 += __shfl_xor(x0, 4); x0 += __shfl_xor(x0, 8); x0 += __shfl_xor(x0, 16);
        x1 += __shfl_xor(x1, 4); x1 += __shfl_xor(x1, 8); x1 += __shfl_xor(x1, 16);
        y0 += __shfl_xor(y0, 4); y0 += __shfl_xor(y0, 8); y0 += __shfl_xor(y0, 16);
        y1 += __shfl_xor(y1, 4); y1 += __shfl_xor(y1, 8); y1 += __shfl_xor(y1, 16);
        a0[k][0] = x0; a0[k][1] = x1; a1[k][0] = y0; a1[k][1] = y1;
    }

    __syncthreads();   // weight/bias staging visibility

    auto fin2 = [&](const f32x2 (&a)[4], int node, int row) {
        const int fq = l & 3;
        const float c = dinv[node] * IS2F;
        uint2 w = hs2q[(size_t)node * 4 + fq];           // self-loop term
        f32x2 s0 = __builtin_amdgcn_cvt_pk_f32_fp8((int)w.x, false);
        f32x2 s1 = __builtin_amdgcn_cvt_pk_f32_fp8((int)w.x, true);
        f32x2 s2 = __builtin_amdgcn_cvt_pk_f32_fp8((int)w.y, false);
        f32x2 s3 = __builtin_amdgcn_cvt_pk_f32_fp8((int)w.y, true);
        // pad feats (>=24): staged 0, b2s 0 -> h2 0
        h2row[row][8 * fq + 0] = fmaxf(c * (a[0][0] + s0[0]) + b2s[8 * fq + 0], 0.f);
        h2row[row][8 * fq + 1] = fmaxf(c * (a[0][1] + s0[1]) + b2s[8 * fq + 1], 0.f);
        h2row[row][8 * fq + 2] = fmaxf(c * (a[1][0] + s1[0]) + b2s[8 * fq + 2], 0.f);
        h2row[row][8 * fq + 3] = fmaxf(c * (a[1][1] + s1[1]) + b2s[8 * fq + 3], 0.f);
        h2row[row][8 * fq + 4] = fmaxf(c * (a[2][0] + s2[0]) + b2s[8 * fq + 4], 0.f);
        h2row[row][8 * fq + 5] = fmaxf(c * (a[2][1] + s2[1]) + b2s[8 * fq + 5], 0.f);
        h2row[row][8 * fq + 6] = fmaxf(c * (a[3][0] + s3[0]) + b2s[8 * fq + 6], 0.f);
        h2row[row][8 * fq + 7] = fmaxf(c * (a[3][1] + s3[1]) + b2s[8 * fq + 7], 0.f);
    };
    if (l < 4) { if (val0) fin2(a0, n0, 2 * g); }
    else if (l < 8) { if (val1) fin2(a1, n1, 2 * g + 1); }

#pragma unroll
    for (int nn = 0; nn < 2; ++nn) {
        const int node = n0 + nn;
        if (node >= N) break;
        const int row = 2 * g + nn;
        if (l < 24) h2out[(size_t)node * 24 + l] = h2row[row][l];
        float val = 0.f;
        if (l < 16) {
            float u = bn1s[l];
#pragma unroll
            for (int k = 0; k < 24; k++) u += h2row[row][k] * Wn1s[k * 16 + l];
            val = fmaxf(u, 0.f) * Wn2s[l];
        }
        val += __shfl_down(val, 8, 16);
        val += __shfl_down(val, 4, 16);
        val += __shfl_down(val, 2, 16);
        val += __shfl_down(val, 1, 16);
        if (l == 0) vout[node] = val + bn2[0];
    }
}

// ---------------------------------------------------------------------------
// One block per graph (precomputed bounds): feature-parallel segment reduction,
// 4x-unrolled pass B, lane-parallel heads.
__global__ __launch_bounds__(256) void graph_kernel(
        const float* __restrict__ v, const float* __restrict__ h2,
        const int* __restrict__ starts,
        const float* __restrict__ Wg, const float* __restrict__ bg,
        const float* __restrict__ Wt, const float* __restrict__ bt,
        const float* __restrict__ Wb1p, const float* __restrict__ bb1p,
        const float* __restrict__ Wb2p, const float* __restrict__ bb2p,
        float* __restrict__ out_t, float* __restrict__ out_n,
        float* __restrict__ bbpre, int N) {
    const int g = blockIdx.x;
    const int tid = threadIdx.x;
    const int lane = tid & 63;
    const int wv = tid >> 6;

    const int start = starts[g];
    const int end = starts[g + 1];

    __shared__ float sm[4];
    __shared__ float pH[4][24], pW[4][24], pS[4];

    // pass A: max of v over the segment (grid-stride, wave reduce)
    float m = -INFINITY;
    for (int idx = start + tid; idx < end; idx += 256) m = fmaxf(m, v[idx]);
#pragma unroll
    for (int off = 32; off > 0; off >>= 1) m = fmaxf(m, __shfl_down(m, off, 64));
    if (lane == 0) sm[wv] = m;
    __syncthreads();
    m = fmaxf(fmaxf(sm[0], sm[1]), fmaxf(sm[2], sm[3]));

    // pass B: feature-parallel accumulation, 4x unrolled (4 node-rows in flight)
    const int half = lane >> 5;
    const int slot = wv * 2 + half;       // 0..7
    const int feat = lane & 31;
    const bool fa = feat < 24;
    float hs = 0.f, ws = 0.f, se = 0.f;
    int i = start + slot;
    for (; i + 24 < end; i += 32) {
        float v0 = v[i], v1 = v[i + 8], v2 = v[i + 16], v3 = v[i + 24];
        float h0 = 0.f, h1 = 0.f, hh2 = 0.f, h3 = 0.f;
        if (fa) {
            h0 = h2[(size_t)i * 24 + feat];
            h1 = h2[(size_t)(i + 8) * 24 + feat];
            hh2 = h2[(size_t)(i + 16) * 24 + feat];
            h3 = h2[(size_t)(i + 24) * 24 + feat];
        }
        float e0 = __expf(v0 - m), e1 = __expf(v1 - m);
        float e2 = __expf(v2 - m), e3 = __expf(v3 - m);
        if (feat == 0) se += (e0 + e1) + (e2 + e3);
        hs += (h0 + h1) + (hh2 + h3);
        ws += (e0 * h0 + e1 * h1) + (e2 * hh2 + e3 * h3);
    }
    for (; i < end; i += 8) {
        float vv = v[i];
        float e = __expf(vv - m);
        if (feat == 0) se += e;
        if (fa) {
            float hv = h2[(size_t)i * 24 + feat];
            hs += hv;
            ws += e * hv;
        }
    }
    // fold the two slots within this wave (lanes differ by 32)
    hs += __shfl_xor(hs, 32, 64);
    ws += __shfl_xor(ws, 32, 64);
    se += __shfl_xor(se, 32, 64);
    if (lane < 24) { pH[wv][lane] = hs; pW[wv][lane] = ws; }
    if (lane == 0) pS[wv] = se;
    __syncthreads();
    const float stot = pS[0] + pS[1] + pS[2] + pS[3];
    const float invs = (stot > 0.f) ? 1.f / stot : 0.f;

    // pass C: write normalized per-node softmax
    for (int idx = start + tid; idx < end; idx += 256)
        out_n[idx] = __expf(v[idx] - m) * invs;

    // heads: wave 0, lane-parallel
    const float denom = fmaxf((float)(end - start), 1.0f);
    if (tid < 32) {
        // t-head: gout[o] per lane, then width-32 shuffle reduce of gout.Wt
        float a = bg[tid];
#pragma unroll
        for (int k = 0; k < 24; k++) {
            float mean_k = (pH[0][k] + pH[1][k] + pH[2][k] + pH[3][k]) / denom;
            a += mean_k * Wg[k * 32 + tid];
        }
        float p0 = a * Wt[tid * 2];
        float p1 = a * Wt[tid * 2 + 1];
#pragma unroll
        for (int off = 16; off > 0; off >>= 1) {
            p0 += __shfl_down(p0, off, 32);
            p1 += __shfl_down(p1, off, 32);
        }
        if (tid == 0) {
            float t0 = p0 + bt[0], t1 = p1 + bt[1];
            float tm = fmaxf(t0, t1);
            float e0 = __expf(t0 - tm), e1 = __expf(t1 - tm);
            float ts = e0 + e1;
            out_t[g * 2 + 0] = e0 / ts;
            out_t[g * 2 + 1] = e1 / ts;
        }
    }
    if (tid < 16) {
        // b-head: u[j] per lane, then width-16 reduce for the 3 columns
        float u = bb1p[tid];
#pragma unroll
        for (int k = 0; k < 24; k++) {
            float bf_k = (pW[0][k] + pW[1][k] + pW[2][k] + pW[3][k]) * invs;
            u += bf_k * Wb1p[k * 16 + tid];
        }
        u = fmaxf(u, 0.f);
        float q0 = u * Wb2p[tid * 3 + 0];
        float q1 = u * Wb2p[tid * 3 + 1];
        float q2 = u * Wb2p[tid * 3 + 2];
#pragma unroll
        for (int off = 8; off > 0; off >>= 1) {
            q0 += __shfl_down(q0, off, 16);
            q1 += __shfl_down(q1, off, 16);
            q2 += __shfl_down(q2, off, 16);
        }
        if (tid == 0) {
            bbpre[g * 3 + 0] = q0 + bb2p[0];
            bbpre[g * 3 + 1] = q1 + bb2p[1];
            bbpre[g * 3 + 2] = q2 + bb2p[2];
        }
    }
}

// column softmax over the 256 graphs (axis=0), 3 columns
__global__ __launch_bounds__(256) void bb_kernel(
        const float* __restrict__ bbpre, float* __restrict__ out_bb) {
    __shared__ float red[NG];
    int g = threadIdx.x;
#pragma unroll
    for (int c = 0; c < 3; c++) {
        float vv = bbpre[g * 3 + c];
        red[g] = vv;
        __syncthreads();
        for (int off = 128; off > 0; off >>= 1) {
            if (g < off) red[g] = fmaxf(red[g], red[g + off]);
            __syncthreads();
        }
        float m = red[0];
        __syncthreads();
        float e = __expf(vv - m);
        red[g] = e;
        __syncthreads();
        for (int off = 128; off > 0; off >>= 1) {
            if (g < off) red[g] += red[g + off];
            __syncthreads();
        }
        float ssum = red[0];
        __syncthreads();
        out_bb[g * 3 + c] = e / ssum;
    }
}

extern "C" void kernel_launch(void* const* d_in, const int* in_sizes, int n_in,
                              void* d_out, int out_size, void* d_ws, size_t ws_size,
                              hipStream_t stream) {
    const float* x   = (const float*)d_in[0];
    const int*   ei  = (const int*)d_in[1];    // [2,E] flat: row=ei[0..E), col=ei[E..2E)
    const int*   bat = (const int*)d_in[2];
    const float* W1  = (const float*)d_in[3];
    const float* b1  = (const float*)d_in[4];
    const float* W2  = (const float*)d_in[5];
    const float* b2  = (const float*)d_in[6];
    const float* Wg  = (const float*)d_in[7];
    const float* bg  = (const float*)d_in[8];
    const float* Wt  = (const float*)d_in[9];
    const float* bt  = (const float*)d_in[10];
    const float* Wn1 = (const float*)d_in[11];
    const float* bn1 = (const float*)d_in[12];
    const float* Wn2 = (const float*)d_in[13];
    const float* bn2 = (const float*)d_in[14];
    const float* Wb1 = (const float*)d_in[15];
    const float* bb1 = (const float*)d_in[16];
    const float* Wb2 = (const float*)d_in[17];
    const float* bb2 = (const float*)d_in[18];

    const int N = in_sizes[2];
    const int E = in_sizes[1] / 2;
    const int NB = (N + 255) >> 8;       // buckets of 256 nodes (<=512)

    // workspace layout (4B units):
    // rowptr[N+1] | dinv[N] | adj[E] | btot[NB] | starts[NG+1] | transient:
    //   build: pairs[E]
    //   compute (aliases pairs region): hs1 fp8 (2(N+1)) -> h2 f32 (24N);
    //     vbuf at +24N; hs2 fp8 at +26N (2(N+1)); bbpre at +28N+4
    // NOTE: adj is followed by btot/starts (>=32 valid words) -- gather reads
    // up to 31 entries past a row end with the value clamped to the zero row.
    auto rnd4 = [](size_t v) { return (v + 3) & ~(size_t)3; };
    size_t oRow = 0;
    size_t oDin = oRow + rnd4((size_t)N + 1);
    size_t oAdj = oDin + rnd4((size_t)N);
    size_t oTot = oAdj + rnd4((size_t)E);
    size_t oSt  = oTot + rnd4((size_t)NB);
    size_t oT   = oSt + rnd4((size_t)NG + 1);

    int*   wsi     = (int*)d_ws;
    float* wsf     = (float*)d_ws;
    int*   rowptr  = wsi + oRow;
    float* dinv    = wsf + oDin;
    int*   adj     = wsi + oAdj;
    int*   btot    = wsi + oTot;
    int*   starts  = wsi + oSt;
    int*   pairs   = wsi + oT;                               // build-time only
    unsigned* hs1b = (unsigned*)(wsf + oT);                  // 2(N+1) units
    float* h2      = wsf + oT;                               // reuses hs1b region after gather1
    float* vbuf    = wsf + oT + (size_t)24 * N;
    unsigned* hs2b = (unsigned*)(wsf + oT + (size_t)26 * N); // 2(N+1) units
    float* bbpre   = wsf + oT + (size_t)28 * N + 4;

    float* out_t  = (float*)d_out;          // [256,2]
    float* out_n  = out_t + 2 * NG;         // [N,1]
    float* out_bb = out_t + 2 * NG + N;     // [256,3]

    const int B = 256;

    // fused CSR build (bounds + hist + scan + scatter + csr in ONE launch)
    (void)hipMemsetAsync(btot, 0, (size_t)NB * sizeof(int), stream);
    {
        void* args[] = {(void*)&ei, (void*)&bat, (void*)&btot, (void*)&pairs,
                        (void*)&rowptr, (void*)&adj, (void*)&dinv, (void*)&starts,
                        (void*)&N, (void*)&E, (void*)&NB};
        (void)hipLaunchCooperativeKernel((void*)build_coop_kernel, dim3(NB), dim3(B),
                                         args, 0, stream);
    }

    // GCN + heads (fp8 staging rows + zero row, 2 nodes/group interleaved gathers)
    hs1_kernel<<<(N + 1 + 7) / 8, B, 0, stream>>>(x, W1, dinv, hs1b, N);
    gather1_kernel<<<(N + 15) / 16, B, 0, stream>>>(rowptr, adj, (const uint2*)hs1b,
                                                    dinv, b1, W2, hs2b, N);
    gather2_kernel<<<(N + 15) / 16, B, 0, stream>>>(rowptr, adj, (const uint2*)hs2b,
                                                    dinv, b2, Wn1, bn1, Wn2, bn2, h2, vbuf, N);
    graph_kernel<<<NG, B, 0, stream>>>(vbuf, h2, starts, Wg, bg, Wt, bt,
                                       Wb1, bb1, Wb2, bb2, out_t, out_n, bbpre, N);
    bb_kernel<<<1, B, 0, stream>>>(bbpre, out_bb);
}

// Round 7
// 291.441 us; speedup vs baseline: 1.3944x; 1.3944x over previous
//
#include <hip/hip_runtime.h>
#include <math.h>

#define NG 256     // NUM_GRAPHS
#define NBLK 256   // blocks in histogram / pair-scatter passes
// bucket = target >> 8 (256 nodes/bucket, NB<=512); src packs in 17 bits (N <= 131072)
// partial records: 2 slots per 16-node block (sorted batch, min graph size >> 16)
#define PSTRIDE 52  // record: [0]=m_b [1]=se_b [2..25]=hs [26..49]=ws

// fp8-e4m3 staging scales (powers of 2: exactly invertible)
#define S1F 16.0f
#define IS1F 0.0625f
#define S2F 64.0f
#define IS2F 0.015625f

typedef __attribute__((ext_vector_type(2))) float f32x2;

__device__ __forceinline__ unsigned enc4(float f0, float f1, float f2, float f3) {
    int r = __builtin_amdgcn_cvt_pk_fp8_f32(f0, f1, 0, false);
    r = __builtin_amdgcn_cvt_pk_fp8_f32(f2, f3, r, true);
    return (unsigned)r;
}
// accumulate 8 fp8 feats (one uint2) into 4 packed f32x2 accumulators
__device__ __forceinline__ void acc8p(uint2 v, f32x2 (&a)[4]) {
    a[0] += __builtin_amdgcn_cvt_pk_f32_fp8((int)v.x, false);
    a[1] += __builtin_amdgcn_cvt_pk_f32_fp8((int)v.x, true);
    a[2] += __builtin_amdgcn_cvt_pk_f32_fp8((int)v.y, false);
    a[3] += __builtin_amdgcn_cvt_pk_f32_fp8((int)v.y, true);
}

// ---------------------------------------------------------------------------
// K1: per-block histogram of edge targets into NB buckets (LDS atomics), then
// reserve this block's range in each bucket via one global atomic per bucket.
__global__ __launch_bounds__(256) void hist_bucket_kernel(
        const int* __restrict__ col, int* __restrict__ blockOff,
        int* __restrict__ bucketTot, int E, int NB) {
    __shared__ int h[512];
    h[threadIdx.x] = 0; h[threadIdx.x + 256] = 0;
    __syncthreads();
    const int chunk = (((E + NBLK - 1) / NBLK) + 3) & ~3;   // 4-aligned per-block chunk
    const int beg = blockIdx.x * chunk;
    const int end = min(beg + chunk, E);
    if ((E & 3) == 0) {
        int e = beg + threadIdx.x * 4;
        for (; e + 3 < end; e += 1024) {
            int4 c = *(const int4*)(col + e);
            atomicAdd(&h[c.x >> 8], 1);
            atomicAdd(&h[c.y >> 8], 1);
            atomicAdd(&h[c.z >> 8], 1);
            atomicAdd(&h[c.w >> 8], 1);
        }
        for (; e < end; e++) atomicAdd(&h[col[e] >> 8], 1);
    } else {
        for (int e = beg + threadIdx.x; e < end; e += 256)
            atomicAdd(&h[col[e] >> 8], 1);
    }
    __syncthreads();
    for (int t = threadIdx.x; t < NB; t += 256) {
        int off = atomicAdd(&bucketTot[t], h[t]);   // reserve range (order arbitrary)
        blockOff[t * NBLK + blockIdx.x] = off;
    }
}

// K2: tiny exclusive scan over bucketTot[NB] -> bucketBase[NB+1]  (NB <= 512)
__global__ __launch_bounds__(512) void tiny_scan_kernel(
        const int* __restrict__ bucketTot, int* __restrict__ bucketBase, int NB) {
    __shared__ int part[512];
    const int t = threadIdx.x;
    int v = (t < NB) ? bucketTot[t] : 0;
    part[t] = v;
    __syncthreads();
    for (int o = 1; o < 512; o <<= 1) {
        int u = (t >= o) ? part[t - o] : 0;
        __syncthreads();
        part[t] += u;
        __syncthreads();
    }
    if (t < NB) bucketBase[t] = part[t] - v;   // exclusive
    if (t == NB) bucketBase[NB] = part[NB - 1];
    if (t == 511 && NB == 512) bucketBase[NB] = part[511];
}

// K3: scatter packed (local_tgt<<17 | src) pairs, grouped by bucket (LDS cursors)
__global__ __launch_bounds__(256) void scatter_pairs_kernel(
        const int* __restrict__ ei, const int* __restrict__ blockOff,
        const int* __restrict__ bucketBase, int* __restrict__ pairs, int E, int NB) {
    __shared__ int cur[512];
    for (int t = threadIdx.x; t < NB; t += 256)
        cur[t] = bucketBase[t] + blockOff[t * NBLK + blockIdx.x];
    __syncthreads();
    const int chunk = (((E + NBLK - 1) / NBLK) + 3) & ~3;
    const int beg = blockIdx.x * chunk;
    const int end = min(beg + chunk, E);
    if ((E & 3) == 0) {
        int e = beg + threadIdx.x * 4;
        for (; e + 3 < end; e += 1024) {
            int4 s = *(const int4*)(ei + e);
            int4 tg = *(const int4*)(ei + E + e);
            int p0 = atomicAdd(&cur[tg.x >> 8], 1);
            pairs[p0] = (int)(((unsigned)(tg.x & 255) << 17) | (unsigned)s.x);
            int p1 = atomicAdd(&cur[tg.y >> 8], 1);
            pairs[p1] = (int)(((unsigned)(tg.y & 255) << 17) | (unsigned)s.y);
            int p2 = atomicAdd(&cur[tg.z >> 8], 1);
            pairs[p2] = (int)(((unsigned)(tg.z & 255) << 17) | (unsigned)s.z);
            int p3 = atomicAdd(&cur[tg.w >> 8], 1);
            pairs[p3] = (int)(((unsigned)(tg.w & 255) << 17) | (unsigned)s.w);
        }
        for (; e < end; e++) {
            int src = ei[e];
            int tgt = ei[E + e];
            int pos = atomicAdd(&cur[tgt >> 8], 1);
            pairs[pos] = (int)(((unsigned)(tgt & 255) << 17) | (unsigned)src);
        }
    } else {
        for (int e = beg + threadIdx.x; e < end; e += 256) {
            int src = ei[e];
            int tgt = ei[E + e];
            int pos = atomicAdd(&cur[tgt >> 8], 1);
            pairs[pos] = (int)(((unsigned)(tgt & 255) << 17) | (unsigned)src);
        }
    }
}

// K4: one block per bucket (256 nodes): LDS hist + scan -> rowptr, dinv, adj
//     + folded segment-bounds pass (starts[] from sorted batch).
__global__ __launch_bounds__(256) void csr_bucket_kernel(
        const int* __restrict__ pairs, const int* __restrict__ bucketBase,
        const int* __restrict__ bat, int* __restrict__ rowptr,
        int* __restrict__ adj, float* __restrict__ dinv,
        int* __restrict__ starts, int N, int E) {
    __shared__ int h[256];
    __shared__ int sc[256];
    __shared__ int cur[256];
    const int b = blockIdx.x, t = threadIdx.x;
    // bounds: starts[g] = lower_bound(batch, g), starts[NG]=N
    {
        const int i = (b << 8) + t;
        if (i < N) {
            int bb = bat[i];
            int bp = (i == 0) ? -1 : bat[i - 1];
            for (int g = bp + 1; g <= bb; g++) starts[g] = i;
            if (i == N - 1)
                for (int g = bb + 1; g <= NG; g++) starts[g] = N;
        }
    }
    const int base = bucketBase[b];
    const int end = bucketBase[b + 1];
    h[t] = 0;
    __syncthreads();
    for (int i = base + t; i < end; i += 256)
        atomicAdd(&h[(unsigned)pairs[i] >> 17], 1);
    __syncthreads();
    const int v = h[t];
    sc[t] = v;
    __syncthreads();
    for (int o = 1; o < 256; o <<= 1) {
        int u = (t >= o) ? sc[t - o] : 0;
        __syncthreads();
        sc[t] += u;
        __syncthreads();
    }
    const int ex = sc[t] - v;
    const int node = (b << 8) + t;
    if (node < N) {
        rowptr[node] = base + ex;
        dinv[node] = rsqrtf((float)v + 1.0f);
    }
    cur[t] = base + ex;
    __syncthreads();
    for (int i = base + t; i < end; i += 256) {
        unsigned p = (unsigned)pairs[i];
        int pos = atomicAdd(&cur[p >> 17], 1);
        adj[pos] = (int)(p & 0x1FFFFu);
    }
    if (b == 0 && t == 0) rowptr[N] = E;
}

// ---------------------------------------------------------------------------
// hs1[i][f] = fp8( (x[i]@W1)[f] * dinv[i] * S1 )   (32 feats -> 32 B rows)
// Row N is all-zero: gathers clamp masked edge slots to index N (exact +0.0).
__global__ __launch_bounds__(256) void hs1_kernel(
        const float* __restrict__ x, const float* __restrict__ W,
        const float* __restrict__ dinv, unsigned* __restrict__ hs, int N) {
    __shared__ float Ws[32 * 32];
    __shared__ float tmp[8][32];
    for (int t = threadIdx.x; t < 1024; t += blockDim.x) Ws[t] = W[t];
    __syncthreads();
    const int tid = threadIdx.x;
    const int node = blockIdx.x * 8 + (tid >> 5);
    const int n = tid >> 5, f = tid & 31;
    if (node < N) {
        const float* xr = x + (size_t)node * 32;
        float acc = 0.f;
#pragma unroll
        for (int k = 0; k < 32; k++) acc += xr[k] * Ws[k * 32 + f];
        tmp[n][f] = acc * dinv[node] * S1F;
        if (f < 8)   // same-wave producer/consumer
            hs[(size_t)node * 8 + f] = enc4(tmp[n][4 * f], tmp[n][4 * f + 1],
                                            tmp[n][4 * f + 2], tmp[n][4 * f + 3]);
    } else if (node == N) {
        if (f < 8) hs[(size_t)N * 8 + f] = 0u;    // zero row
    }
}

// ---------------------------------------------------------------------------
// gather layer 1: 2 nodes per 32-lane group (16 nodes/block). Uniform masked
// 32-edge loop per node, both nodes' loads interleaved. Masked slots clamp
// the adj index to N (zero row).
__global__ __launch_bounds__(256) void gather1_kernel(
        const int* __restrict__ rowptr, const int* __restrict__ adj,
        const uint2* __restrict__ hs1q, const float* __restrict__ dinv,
        const float* __restrict__ b1, const float* __restrict__ W2,
        unsigned* __restrict__ hs2out, int N) {
    __shared__ float W2s[32 * 24];
    __shared__ float b1s[32];
    __shared__ float h1row[16][32];
    __shared__ float hs2t[16][32];
    const int tid = threadIdx.x;
    for (int t = tid; t < 768; t += 256) W2s[t] = W2[t];
    if (tid < 32) b1s[tid] = b1[tid];
    if (blockIdx.x == 0 && tid < 8) hs2out[(size_t)N * 8 + tid] = 0u;  // zero row for gather2

    const int g = tid >> 5;          // group 0..7
    const int l = tid & 31;
    const int f8 = l & 3;            // feature octet
    const int e8 = l >> 2;           // edge slot 0..7
    const int n0 = (blockIdx.x * 8 + g) * 2;
    const int n1 = n0 + 1;
    const bool val0 = n0 < N;
    const bool val1 = n1 < N;

    int beg0 = 0, cnt0 = 0, beg1 = 0, cnt1 = 0;
    if (val0) {
        int2 rp = *(const int2*)(rowptr + n0);       // n0 even -> 8B aligned
        beg0 = rp.x; cnt0 = rp.y - rp.x;
        if (val1) { int e2 = rowptr[n0 + 2]; beg1 = rp.y; cnt1 = e2 - rp.y; }
    }
    const int* ap0 = adj + beg0;
    const int* ap1 = adj + beg1;
    f32x2 a0[4], a1[4];
#pragma unroll
    for (int k = 0; k < 4; k++) { a0[k][0] = 0.f; a0[k][1] = 0.f; a1[k][0] = 0.f; a1[k][1] = 0.f; }

    const int jmax = max(cnt0, cnt1);
    for (int j = 0; j < jmax; j += 32) {
        const int i0 = j + e8, i1 = j + 8 + e8, i2 = j + 16 + e8, i3 = j + 24 + e8;
        int sA0 = ap0[i0], sA1 = ap0[i1], sA2 = ap0[i2], sA3 = ap0[i3];
        int sB0 = ap1[i0], sB1 = ap1[i1], sB2 = ap1[i2], sB3 = ap1[i3];
        if (i0 >= cnt0) sA0 = N; if (i1 >= cnt0) sA1 = N;
        if (i2 >= cnt0) sA2 = N; if (i3 >= cnt0) sA3 = N;
        if (i0 >= cnt1) sB0 = N; if (i1 >= cnt1) sB1 = N;
        if (i2 >= cnt1) sB2 = N; if (i3 >= cnt1) sB3 = N;
        uint2 vA0 = hs1q[(size_t)sA0 * 4 + f8];
        uint2 vA1 = hs1q[(size_t)sA1 * 4 + f8];
        uint2 vA2 = hs1q[(size_t)sA2 * 4 + f8];
        uint2 vA3 = hs1q[(size_t)sA3 * 4 + f8];
        uint2 vB0 = hs1q[(size_t)sB0 * 4 + f8];
        uint2 vB1 = hs1q[(size_t)sB1 * 4 + f8];
        uint2 vB2 = hs1q[(size_t)sB2 * 4 + f8];
        uint2 vB3 = hs1q[(size_t)sB3 * 4 + f8];
        acc8p(vA0, a0); acc8p(vA1, a0); acc8p(vA2, a0); acc8p(vA3, a0);
        acc8p(vB0, a1); acc8p(vB1, a1); acc8p(vB2, a1); acc8p(vB3, a1);
    }
#pragma unroll
    for (int k = 0; k < 4; k++) {                // fold 8 edge slots (lane bits 2,3,4)
        float x0 = a0[k][0], x1 = a0[k][1], y0 = a1[k][0], y1 = a1[k][1];
        x0 += __shfl_xor(x0, 4); x0 += __shfl_xor(x0, 8); x0 += __shfl_xor(x0, 16);
        x1 += __shfl_xor(x1, 4); x1 += __shfl_xor(x1, 8); x1 += __shfl_xor(x1, 16);
        y0 += __shfl_xor(y0, 4); y0 += __shfl_xor(y0, 8); y0 += __shfl_xor(y0, 16);
        y1 += __shfl_xor(y1, 4); y1 += __shfl_xor(y1, 8); y1 += __shfl_xor(y1, 16);
        a0[k][0] = x0; a0[k][1] = x1; a1[k][0] = y0; a1[k][1] = y1;
    }

    __syncthreads();   // weight/bias staging visibility (all threads reach here)

    auto fin1 = [&](const f32x2 (&a)[4], int node, int row) {
        const int fq = l & 3;
        const float c = dinv[node] * IS1F;
        uint2 w = hs1q[(size_t)node * 4 + fq];           // self-loop term
        f32x2 s0 = __builtin_amdgcn_cvt_pk_f32_fp8((int)w.x, false);
        f32x2 s1 = __builtin_amdgcn_cvt_pk_f32_fp8((int)w.x, true);
        f32x2 s2 = __builtin_amdgcn_cvt_pk_f32_fp8((int)w.y, false);
        f32x2 s3 = __builtin_amdgcn_cvt_pk_f32_fp8((int)w.y, true);
        h1row[row][8 * fq + 0] = fmaxf(c * (a[0][0] + s0[0]) + b1s[8 * fq + 0], 0.f);
        h1row[row][8 * fq + 1] = fmaxf(c * (a[0][1] + s0[1]) + b1s[8 * fq + 1], 0.f);
        h1row[row][8 * fq + 2] = fmaxf(c * (a[1][0] + s1[0]) + b1s[8 * fq + 2], 0.f);
        h1row[row][8 * fq + 3] = fmaxf(c * (a[1][1] + s1[1]) + b1s[8 * fq + 3], 0.f);
        h1row[row][8 * fq + 4] = fmaxf(c * (a[2][0] + s2[0]) + b1s[8 * fq + 4], 0.f);
        h1row[row][8 * fq + 5] = fmaxf(c * (a[2][1] + s2[1]) + b1s[8 * fq + 5], 0.f);
        h1row[row][8 * fq + 6] = fmaxf(c * (a[3][0] + s3[0]) + b1s[8 * fq + 6], 0.f);
        h1row[row][8 * fq + 7] = fmaxf(c * (a[3][1] + s3[1]) + b1s[8 * fq + 7], 0.f);
    };
    if (l < 4) { if (val0) fin1(a0, n0, 2 * g); }
    else if (l < 8) { if (val1) fin1(a1, n1, 2 * g + 1); }

    // @W2 + fp8 stage, two serial passes (same-wave producer/consumer via LDS)
#pragma unroll
    for (int nn = 0; nn < 2; ++nn) {
        const int node = n0 + nn;
        if (node >= N) break;
        const int row = 2 * g + nn;
        const float sc = dinv[node] * S2F;
        float aa = 0.f;
        if (l < 24) {
#pragma unroll
            for (int k = 0; k < 32; k++) aa += h1row[row][k] * W2s[k * 24 + l];
        }
        hs2t[row][l] = (l < 24) ? aa * sc : 0.f;
        if (l < 8)
            hs2out[(size_t)node * 8 + l] = enc4(hs2t[row][4 * l], hs2t[row][4 * l + 1],
                                                hs2t[row][4 * l + 2], hs2t[row][4 * l + 3]);
    }
}

// gather layer 2: same 2-node structure; finalize keeps h2 in LDS only,
// fuses node-MLP -> v, and emits per-block per-graph partial records
// {m_b, se_b, hs_b[24], ws_b[24]} (2 slots; sorted batch, graphs >> 16 nodes).
__global__ __launch_bounds__(256) void gather2_kernel(
        const int* __restrict__ rowptr, const int* __restrict__ adj,
        const uint2* __restrict__ hs2q, const float* __restrict__ dinv,
        const float* __restrict__ b2,
        const float* __restrict__ Wn1, const float* __restrict__ bn1,
        const float* __restrict__ Wn2, const float* __restrict__ bn2,
        const int* __restrict__ bat, float* __restrict__ vout,
        float* __restrict__ pbuf, int* __restrict__ pg, int N) {
    __shared__ float Wn1s[24 * 16];
    __shared__ float b2s[32], bn1s[16], Wn2s[16];
    __shared__ float h2row[16][32];
    __shared__ float varr[16];
    __shared__ int gidArr[16];
    const int tid = threadIdx.x;
    for (int t = tid; t < 384; t += 256) Wn1s[t] = Wn1[t];
    if (tid < 32) b2s[tid] = (tid < 24) ? b2[tid] : 0.f;
    if (tid < 16) { bn1s[tid] = bn1[tid]; Wn2s[tid] = Wn2[tid]; gidArr[tid] = -1; }

    const int g = tid >> 5;
    const int l = tid & 31;
    const int f8 = l & 3;
    const int e8 = l >> 2;
    const int n0 = (blockIdx.x * 8 + g) * 2;
    const int n1 = n0 + 1;
    const bool val0 = n0 < N;
    const bool val1 = n1 < N;

    int beg0 = 0, cnt0 = 0, beg1 = 0, cnt1 = 0;
    if (val0) {
        int2 rp = *(const int2*)(rowptr + n0);
        beg0 = rp.x; cnt0 = rp.y - rp.x;
        if (val1) { int e2 = rowptr[n0 + 2]; beg1 = rp.y; cnt1 = e2 - rp.y; }
    }
    const int* ap0 = adj + beg0;
    const int* ap1 = adj + beg1;
    f32x2 a0[4], a1[4];
#pragma unroll
    for (int k = 0; k < 4; k++) { a0[k][0] = 0.f; a0[k][1] = 0.f; a1[k][0] = 0.f; a1[k][1] = 0.f; }

    const int jmax = max(cnt0, cnt1);
    for (int j = 0; j < jmax; j += 32) {
        const int i0 = j + e8, i1 = j + 8 + e8, i2 = j + 16 + e8, i3 = j + 24 + e8;
        int sA0 = ap0[i0], sA1 = ap0[i1], sA2 = ap0[i2], sA3 = ap0[i3];
        int sB0 = ap1[i0], sB1 = ap1[i1], sB2 = ap1[i2], sB3 = ap1[i3];
        if (i0 >= cnt0) sA0 = N; if (i1 >= cnt0) sA1 = N;
        if (i2 >= cnt0) sA2 = N; if (i3 >= cnt0) sA3 = N;
        if (i0 >= cnt1) sB0 = N; if (i1 >= cnt1) sB1 = N;
        if (i2 >= cnt1) sB2 = N; if (i3 >= cnt1) sB3 = N;
        uint2 vA0 = hs2q[(size_t)sA0 * 4 + f8];
        uint2 vA1 = hs2q[(size_t)sA1 * 4 + f8];
        uint2 vA2 = hs2q[(size_t)sA2 * 4 + f8];
        uint2 vA3 = hs2q[(size_t)sA3 * 4 + f8];
        uint2 vB0 = hs2q[(size_t)sB0 * 4 + f8];
        uint2 vB1 = hs2q[(size_t)sB1 * 4 + f8];
        uint2 vB2 = hs2q[(size_t)sB2 * 4 + f8];
        uint2 vB3 = hs2q[(size_t)sB3 * 4 + f8];
        acc8p(vA0, a0); acc8p(vA1, a0); acc8p(vA2, a0); acc8p(vA3, a0);
        acc8p(vB0, a1); acc8p(vB1, a1); acc8p(vB2, a1); acc8p(vB3, a1);
    }
#pragma unroll
    for (int k = 0; k < 4; k++) {
        float x0 = a0[k][0], x1 = a0[k][1], y0 = a1[k][0], y1 = a1[k][1];
        x0 += __shfl_xor(x0, 4); x0 += __shfl_xor(x0, 8); x0 += __shfl_xor(x0, 16);
        x1 += __shfl_xor(x1, 4); x1 += __shfl_xor(x1, 8); x1 += __shfl_xor(x1, 16);
        y0 += __shfl_xor(y0, 4); y0 += __shfl_xor(y0, 8); y0 += __shfl_xor(y0, 16);
        y1 += __shfl_xor(y1, 4); y1 += __shfl_xor(y1, 8); y1 += __shfl_xor(y1, 16);
        a0[k][0] = x0; a0[k][1] = x1; a1[k][0] = y0; a1[k][1] = y1;
    }

    __syncthreads();   // weight/bias staging visibility

    auto fin2 = [&](const f32x2 (&a)[4], int node, int row) {
        const int fq = l & 3;
        const float c = dinv[node] * IS2F;
        uint2 w = hs2q[(size_t)node * 4 + fq];           // self-loop term
        f32x2 s0 = __builtin_amdgcn_cvt_pk_f32_fp8((int)w.x, false);
        f32x2 s1 = __builtin_amdgcn_cvt_pk_f32_fp8((int)w.x, true);
        f32x2 s2 = __builtin_amdgcn_cvt_pk_f32_fp8((int)w.y, false);
        f32x2 s3 = __builtin_amdgcn_cvt_pk_f32_fp8((int)w.y, true);
        // pad feats (>=24): staged 0, b2s 0 -> h2 0
        h2row[row][8 * fq + 0] = fmaxf(c * (a[0][0] + s0[0]) + b2s[8 * fq + 0], 0.f);
        h2row[row][8 * fq + 1] = fmaxf(c * (a[0][1] + s0[1]) + b2s[8 * fq + 1], 0.f);
        h2row[row][8 * fq + 2] = fmaxf(c * (a[1][0] + s1[0]) + b2s[8 * fq + 2], 0.f);
        h2row[row][8 * fq + 3] = fmaxf(c * (a[1][1] + s1[1]) + b2s[8 * fq + 3], 0.f);
        h2row[row][8 * fq + 4] = fmaxf(c * (a[2][0] + s2[0]) + b2s[8 * fq + 4], 0.f);
        h2row[row][8 * fq + 5] = fmaxf(c * (a[2][1] + s2[1]) + b2s[8 * fq + 5], 0.f);
        h2row[row][8 * fq + 6] = fmaxf(c * (a[3][0] + s3[0]) + b2s[8 * fq + 6], 0.f);
        h2row[row][8 * fq + 7] = fmaxf(c * (a[3][1] + s3[1]) + b2s[8 * fq + 7], 0.f);
    };
    if (l < 4) { if (val0) fin2(a0, n0, 2 * g); }
    else if (l < 8) { if (val1) fin2(a1, n1, 2 * g + 1); }

#pragma unroll
    for (int nn = 0; nn < 2; ++nn) {
        const int node = n0 + nn;
        if (node >= N) break;
        const int row = 2 * g + nn;
        float val = 0.f;
        if (l < 16) {
            float u = bn1s[l];
#pragma unroll
            for (int k = 0; k < 24; k++) u += h2row[row][k] * Wn1s[k * 16 + l];
            val = fmaxf(u, 0.f) * Wn2s[l];
        }
        val += __shfl_down(val, 8, 16);
        val += __shfl_down(val, 4, 16);
        val += __shfl_down(val, 2, 16);
        val += __shfl_down(val, 1, 16);
        if (l == 0) { float vv = val + bn2[0]; vout[node] = vv; varr[row] = vv; }
        if (l == 1) gidArr[row] = bat[node];
    }

    __syncthreads();   // h2row/varr/gid visible to wave 0

    if (tid < 64) {
        // base graph of this block
        int gbase = 0x7fffffff;
#pragma unroll
        for (int r = 0; r < 16; r++) {
            int gg = gidArr[r];
            if (gg >= 0 && gg < gbase) gbase = gg;
        }
        // per-slot max (2 slots; redundant per lane)
        float m0 = -INFINITY, m1 = -INFINITY;
#pragma unroll
        for (int r = 0; r < 16; r++) {
            int gg = gidArr[r];
            if (gg >= 0) {
                if (gg == gbase) m0 = fmaxf(m0, varr[r]);
                else m1 = fmaxf(m1, varr[r]);
            }
        }
        // accumulate hs/ws (lane f<24) and se (lane 24 writes)
        const int f = tid;
        float hs0 = 0.f, ws0 = 0.f, se0 = 0.f;
        float hs1v = 0.f, ws1v = 0.f, se1v = 0.f;
#pragma unroll
        for (int r = 0; r < 16; r++) {
            int gg = gidArr[r];
            if (gg < 0) continue;
            float h = (f < 24) ? h2row[r][f] : 0.f;
            if (gg == gbase) {
                float e = __expf(varr[r] - m0);
                hs0 += h; ws0 += e * h; se0 += e;
            } else {
                float e = __expf(varr[r] - m1);
                hs1v += h; ws1v += e * h; se1v += e;
            }
        }
        const int bidx = blockIdx.x * 2;
        const bool p0 = (m0 != -INFINITY);
        const bool p1 = (m1 != -INFINITY);
        if (tid == 25) {
            pg[bidx] = p0 ? gbase : -1;
            pg[bidx + 1] = p1 ? (gbase + 1) : -1;
        }
        size_t off0 = (size_t)bidx * PSTRIDE;
        size_t off1 = (size_t)(bidx + 1) * PSTRIDE;
        if (p0) {
            if (tid == 24) { pbuf[off0] = m0; pbuf[off0 + 1] = se0; }
            if (tid < 24) { pbuf[off0 + 2 + tid] = hs0; pbuf[off0 + 26 + tid] = ws0; }
        }
        if (p1) {
            if (tid == 24) { pbuf[off1] = m1; pbuf[off1 + 1] = se1v; }
            if (tid < 24) { pbuf[off1 + 2 + tid] = hs1v; pbuf[off1 + 26 + tid] = ws1v; }
        }
    }
}

// ---------------------------------------------------------------------------
// One block per graph: reduce partial records -> m, s, hs[24], bf[24];
// softmax write (pass C); heads; last block computes the column softmax (bb).
__global__ __launch_bounds__(256) void graph_kernel(
        const float* __restrict__ v, const float* __restrict__ pbuf,
        const int* __restrict__ pg, const int* __restrict__ starts,
        const float* __restrict__ Wg, const float* __restrict__ bg,
        const float* __restrict__ Wt, const float* __restrict__ bt,
        const float* __restrict__ Wb1p, const float* __restrict__ bb1p,
        const float* __restrict__ Wb2p, const float* __restrict__ bb2p,
        float* __restrict__ out_t, float* __restrict__ out_n,
        float* __restrict__ bbpre, float* __restrict__ out_bb,
        int* __restrict__ cnt, int N) {
    const int g = blockIdx.x;
    const int tid = threadIdx.x;
    const int lane = tid & 63;
    const int wv = tid >> 6;
    const int start = starts[g];
    const int end = starts[g + 1];

    __shared__ float sm[4];
    __shared__ float hsumL[24], bfL[24];
    __shared__ float invsS;
    __shared__ float red[NG];
    __shared__ int lastFlag;

    int idx0 = 0, nrec = 0;
    if (end > start) {
        int rb0 = start >> 4, rb1 = (end - 1) >> 4;
        idx0 = rb0 * 2;
        nrec = (rb1 - rb0 + 1) * 2;
    }
    // stage 1: global max over matching records
    float m = -INFINITY;
    for (int k = tid; k < nrec; k += 256)
        if (pg[idx0 + k] == g) m = fmaxf(m, pbuf[(size_t)(idx0 + k) * PSTRIDE]);
#pragma unroll
    for (int off = 32; off > 0; off >>= 1) m = fmaxf(m, __shfl_down(m, off, 64));
    if (lane == 0) sm[wv] = m;
    __syncthreads();
    m = fmaxf(fmaxf(sm[0], sm[1]), fmaxf(sm[2], sm[3]));

    // stage 2: rescaled sums (feat lanes 0..23; lane 24 = se)
    if (tid < 25) {
        float hs = 0.f, bf = 0.f, se = 0.f;
        for (int k = 0; k < nrec; k++) {
            int idx = idx0 + k;
            if (pg[idx] != g) continue;
            const float* rec = pbuf + (size_t)idx * PSTRIDE;
            float w = __expf(rec[0] - m);
            if (tid < 24) { hs += rec[2 + tid]; bf += rec[26 + tid] * w; }
            else se += rec[1] * w;
        }
        if (tid < 24) { hsumL[tid] = hs; bfL[tid] = bf; }
        else invsS = (se > 0.f) ? 1.f / se : 0.f;
    }
    __syncthreads();
    const float invs = invsS;

    // pass C: normalized per-node softmax
    for (int idx = start + tid; idx < end; idx += 256)
        out_n[idx] = __expf(v[idx] - m) * invs;

    // heads
    const float denom = fmaxf((float)(end - start), 1.0f);
    if (tid < 32) {
        float a = bg[tid];
#pragma unroll
        for (int k = 0; k < 24; k++) a += (hsumL[k] / denom) * Wg[k * 32 + tid];
        float p0 = a * Wt[tid * 2];
        float p1 = a * Wt[tid * 2 + 1];
#pragma unroll
        for (int off = 16; off > 0; off >>= 1) {
            p0 += __shfl_down(p0, off, 32);
            p1 += __shfl_down(p1, off, 32);
        }
        if (tid == 0) {
            float t0 = p0 + bt[0], t1 = p1 + bt[1];
            float tm = fmaxf(t0, t1);
            float e0 = __expf(t0 - tm), e1 = __expf(t1 - tm);
            float ts = e0 + e1;
            out_t[g * 2 + 0] = e0 / ts;
            out_t[g * 2 + 1] = e1 / ts;
        }
    }
    if (tid < 16) {
        float u = bb1p[tid];
#pragma unroll
        for (int k = 0; k < 24; k++) u += (bfL[k] * invs) * Wb1p[k * 16 + tid];
        u = fmaxf(u, 0.f);
        float q0 = u * Wb2p[tid * 3 + 0];
        float q1 = u * Wb2p[tid * 3 + 1];
        float q2 = u * Wb2p[tid * 3 + 2];
#pragma unroll
        for (int off = 8; off > 0; off >>= 1) {
            q0 += __shfl_down(q0, off, 16);
            q1 += __shfl_down(q1, off, 16);
            q2 += __shfl_down(q2, off, 16);
        }
        if (tid == 0) {
            bbpre[g * 3 + 0] = q0 + bb2p[0];
            bbpre[g * 3 + 1] = q1 + bb2p[1];
            bbpre[g * 3 + 2] = q2 + bb2p[2];
        }
    }

    // last block computes the column softmax over graphs (bb)
    __syncthreads();
    if (tid == 0) {
        __threadfence();
        int old = atomicAdd(cnt, 1);
        lastFlag = (old == NG - 1) ? 1 : 0;
    }
    __syncthreads();
    if (lastFlag) {
        __threadfence();
        const int gg = tid;   // 256 threads == NG
#pragma unroll
        for (int c = 0; c < 3; c++) {
            float vv = bbpre[gg * 3 + c];
            red[gg] = vv;
            __syncthreads();
            for (int off = 128; off > 0; off >>= 1) {
                if (gg < off) red[gg] = fmaxf(red[gg], red[gg + off]);
                __syncthreads();
            }
            float mm = red[0];
            __syncthreads();
            float e = __expf(vv - mm);
            red[gg] = e;
            __syncthreads();
            for (int off = 128; off > 0; off >>= 1) {
                if (gg < off) red[gg] += red[gg + off];
                __syncthreads();
            }
            float ssum = red[0];
            __syncthreads();
            out_bb[gg * 3 + c] = e / ssum;
        }
    }
}

extern "C" void kernel_launch(void* const* d_in, const int* in_sizes, int n_in,
                              void* d_out, int out_size, void* d_ws, size_t ws_size,
                              hipStream_t stream) {
    const float* x   = (const float*)d_in[0];
    const int*   ei  = (const int*)d_in[1];    // [2,E] flat: row=ei[0..E), col=ei[E..2E)
    const int*   bat = (const int*)d_in[2];
    const float* W1  = (const float*)d_in[3];
    const float* b1  = (const float*)d_in[4];
    const float* W2  = (const float*)d_in[5];
    const float* b2  = (const float*)d_in[6];
    const float* Wg  = (const float*)d_in[7];
    const float* bg  = (const float*)d_in[8];
    const float* Wt  = (const float*)d_in[9];
    const float* bt  = (const float*)d_in[10];
    const float* Wn1 = (const float*)d_in[11];
    const float* bn1 = (const float*)d_in[12];
    const float* Wn2 = (const float*)d_in[13];
    const float* bn2 = (const float*)d_in[14];
    const float* Wb1 = (const float*)d_in[15];
    const float* bb1 = (const float*)d_in[16];
    const float* Wb2 = (const float*)d_in[17];
    const float* bb2 = (const float*)d_in[18];

    const int N = in_sizes[2];
    const int E = in_sizes[1] / 2;
    const int NB = (N + 255) >> 8;       // buckets of 256 nodes
    const int M = NB * NBLK;             // blockOff matrix size
    const int NBLK2 = (N + 15) / 16;     // gather2 blocks (16 nodes each)

    // workspace layout (4B units) -- bbase now has a DEDICATED header slot
    // (round-6 crash: bbase placed inside the pairs region got clobbered):
    // rowptr[N+1] | dinv[N] | adj[E] | btot[NB]+cnt[1] | starts[NG+1] |
    // bbase[NB+1] | transient:
    //   build:   blockOff[M] | pairs[E]
    //   compute (overlays build): hs1 fp8 2(N+1) | hs2 fp8 2(N+1) | vbuf N |
    //            pbuf 2*NBLK2*PSTRIDE | pg 2*NBLK2 | bbpre 3*NG
    auto rnd4 = [](size_t v) { return (v + 3) & ~(size_t)3; };
    size_t oRow = 0;
    size_t oDin = oRow + rnd4((size_t)N + 1);
    size_t oAdj = oDin + rnd4((size_t)N);
    size_t oTot = oAdj + rnd4((size_t)E);
    size_t oSt  = oTot + rnd4((size_t)NB + 1);
    size_t oBB  = oSt + rnd4((size_t)NG + 1);
    size_t oT   = oBB + rnd4((size_t)NB + 1);

    int*   wsi     = (int*)d_ws;
    float* wsf     = (float*)d_ws;
    int*   rowptr  = wsi + oRow;
    float* dinv    = wsf + oDin;
    int*   adj     = wsi + oAdj;
    int*   btot    = wsi + oTot;
    int*   cnt     = wsi + oTot + NB;
    int*   starts  = wsi + oSt;
    int*   bbase   = wsi + oBB;
    int*   blkoff  = wsi + oT;
    int*   pairs   = wsi + oT + rnd4((size_t)M);
    // compute region overlays blkoff/pairs (build data dead before hs1 runs)
    size_t cb = oT;
    unsigned* hs1b = (unsigned*)(wsf + cb);                       // 2(N+1)
    unsigned* hs2b = (unsigned*)(wsf + cb + 2 * ((size_t)N + 1)); // 2(N+1)
    float* vbuf    = wsf + cb + 4 * ((size_t)N + 1);
    float* pbuf    = wsf + cb + 4 * ((size_t)N + 1) + rnd4((size_t)N);
    int*   pg      = wsi + cb + 4 * ((size_t)N + 1) + rnd4((size_t)N)
                         + rnd4((size_t)2 * NBLK2 * PSTRIDE);
    float* bbpre   = (float*)(pg + rnd4((size_t)2 * NBLK2));

    float* out_t  = (float*)d_out;          // [256,2]
    float* out_n  = out_t + 2 * NG;         // [N,1]
    float* out_bb = out_t + 2 * NG + N;     // [256,3]

    const int B = 256;

    // CSR build (bounds folded into csr_bucket)
    (void)hipMemsetAsync(btot, 0, (size_t)(NB + 1) * sizeof(int), stream);
    hist_bucket_kernel<<<NBLK, B, 0, stream>>>(ei + E, blkoff, btot, E, NB);
    tiny_scan_kernel<<<1, 512, 0, stream>>>(btot, bbase, NB);
    scatter_pairs_kernel<<<NBLK, B, 0, stream>>>(ei, blkoff, bbase, pairs, E, NB);
    csr_bucket_kernel<<<NB, B, 0, stream>>>(pairs, bbase, bat, rowptr, adj, dinv,
                                            starts, N, E);

    // GCN + heads
    hs1_kernel<<<(N + 1 + 7) / 8, B, 0, stream>>>(x, W1, dinv, hs1b, N);
    gather1_kernel<<<(N + 15) / 16, B, 0, stream>>>(rowptr, adj, (const uint2*)hs1b,
                                                    dinv, b1, W2, hs2b, N);
    gather2_kernel<<<NBLK2, B, 0, stream>>>(rowptr, adj, (const uint2*)hs2b,
                                            dinv, b2, Wn1, bn1, Wn2, bn2,
                                            bat, vbuf, pbuf, pg, N);
    graph_kernel<<<NG, B, 0, stream>>>(vbuf, pbuf, pg, starts, Wg, bg, Wt, bt,
                                       Wb1, bb1, Wb2, bb2, out_t, out_n,
                                       bbpre, out_bb, cnt, N);
}

// Round 8
// 278.246 us; speedup vs baseline: 1.4606x; 1.0474x over previous
//
#include <hip/hip_runtime.h>
#include <math.h>

#define NG 256     // NUM_GRAPHS
#define NBLK 256   // blocks in histogram / pair-scatter passes
// bucket = target >> 8 (256 nodes/bucket, NB<=512); src packs in 17 bits (N <= 131072)

// fp8-e4m3 staging scales (powers of 2: exactly invertible)
#define S1F 16.0f
#define IS1F 0.0625f
#define S2F 64.0f
#define IS2F 0.015625f

typedef __attribute__((ext_vector_type(2))) float f32x2;

__device__ __forceinline__ unsigned enc4(float f0, float f1, float f2, float f3) {
    int r = __builtin_amdgcn_cvt_pk_fp8_f32(f0, f1, 0, false);
    r = __builtin_amdgcn_cvt_pk_fp8_f32(f2, f3, r, true);
    return (unsigned)r;
}
// accumulate 8 fp8 feats (one uint2) into 4 packed f32x2 accumulators
__device__ __forceinline__ void acc8p(uint2 v, f32x2 (&a)[4]) {
    a[0] += __builtin_amdgcn_cvt_pk_f32_fp8((int)v.x, false);
    a[1] += __builtin_amdgcn_cvt_pk_f32_fp8((int)v.x, true);
    a[2] += __builtin_amdgcn_cvt_pk_f32_fp8((int)v.y, false);
    a[3] += __builtin_amdgcn_cvt_pk_f32_fp8((int)v.y, true);
}

// local exclusive scan of btot[NB] (NB<=512) -> A[0..512]; A[NB] = total.
// Pure integer function of btot (final after hist dispatch) -> bit-identical
// across blocks; replaces the tiny_scan dispatch.
__device__ __forceinline__ void scan_btot_lds(
        const int* __restrict__ btot, int NB, int t,
        int* A, int* C, int* D) {
    const int v0 = (t < NB) ? btot[t] : 0;
    const int v1 = (t + 256 < NB) ? btot[t + 256] : 0;
    C[t] = v0; C[t + 256] = v1;
    __syncthreads();
    int* src = C; int* dst = D;
    for (int off = 1; off < 512; off <<= 1) {
        int a0 = src[t] + ((t >= off) ? src[t - off] : 0);
        int a1 = src[t + 256] + src[t + 256 - off];   // t+256 >= off always (off<=256)
        dst[t] = a0; dst[t + 256] = a1;
        __syncthreads();
        int* tm = src; src = dst; dst = tm;
    }
    A[t] = src[t] - v0;              // exclusive prefix
    A[t + 256] = src[t + 256] - v1;  // for t+256 >= NB this equals the total
    if (t == 0) A[512] = src[511];
    __syncthreads();
}

// ---------------------------------------------------------------------------
// K1: per-block histogram of edge targets into NB buckets (LDS atomics), then
// reserve this block's range in each bucket via one global atomic per bucket.
__global__ __launch_bounds__(256) void hist_bucket_kernel(
        const int* __restrict__ col, int* __restrict__ blockOff,
        int* __restrict__ bucketTot, int E, int NB) {
    __shared__ int h[512];
    h[threadIdx.x] = 0; h[threadIdx.x + 256] = 0;
    __syncthreads();
    const int chunk = (((E + NBLK - 1) / NBLK) + 3) & ~3;   // 4-aligned per-block chunk
    const int beg = blockIdx.x * chunk;
    const int end = min(beg + chunk, E);
    if ((E & 3) == 0) {
        int e = beg + threadIdx.x * 4;
        for (; e + 3 < end; e += 1024) {
            int4 c = *(const int4*)(col + e);
            atomicAdd(&h[c.x >> 8], 1);
            atomicAdd(&h[c.y >> 8], 1);
            atomicAdd(&h[c.z >> 8], 1);
            atomicAdd(&h[c.w >> 8], 1);
        }
        for (; e < end; e++) atomicAdd(&h[col[e] >> 8], 1);
    } else {
        for (int e = beg + threadIdx.x; e < end; e += 256)
            atomicAdd(&h[col[e] >> 8], 1);
    }
    __syncthreads();
    for (int t = threadIdx.x; t < NB; t += 256) {
        int off = atomicAdd(&bucketTot[t], h[t]);   // reserve range (order arbitrary)
        blockOff[t * NBLK + blockIdx.x] = off;
    }
}

// K2: scatter packed (local_tgt<<17 | src) pairs, grouped by bucket.
// Bucket bases computed locally via scan_btot_lds (no scan dispatch).
__global__ __launch_bounds__(256) void scatter_pairs_kernel(
        const int* __restrict__ ei, const int* __restrict__ blockOff,
        const int* __restrict__ btot, int* __restrict__ pairs, int E, int NB) {
    __shared__ int A[513];
    __shared__ int C[512];
    __shared__ int D[512];
    __shared__ int cur[512];
    const int t = threadIdx.x;
    scan_btot_lds(btot, NB, t, A, C, D);
    cur[t] = A[t] + blockOff[t * NBLK + blockIdx.x];
    if (t + 256 < NB) cur[t + 256] = A[t + 256] + blockOff[(t + 256) * NBLK + blockIdx.x];
    __syncthreads();
    const int chunk = (((E + NBLK - 1) / NBLK) + 3) & ~3;
    const int beg = blockIdx.x * chunk;
    const int end = min(beg + chunk, E);
    if ((E & 3) == 0) {
        int e = beg + t * 4;
        for (; e + 3 < end; e += 1024) {
            int4 s = *(const int4*)(ei + e);
            int4 tg = *(const int4*)(ei + E + e);
            int p0 = atomicAdd(&cur[tg.x >> 8], 1);
            pairs[p0] = (int)(((unsigned)(tg.x & 255) << 17) | (unsigned)s.x);
            int p1 = atomicAdd(&cur[tg.y >> 8], 1);
            pairs[p1] = (int)(((unsigned)(tg.y & 255) << 17) | (unsigned)s.y);
            int p2 = atomicAdd(&cur[tg.z >> 8], 1);
            pairs[p2] = (int)(((unsigned)(tg.z & 255) << 17) | (unsigned)s.z);
            int p3 = atomicAdd(&cur[tg.w >> 8], 1);
            pairs[p3] = (int)(((unsigned)(tg.w & 255) << 17) | (unsigned)s.w);
        }
        for (; e < end; e++) {
            int src = ei[e];
            int tgt = ei[E + e];
            int pos = atomicAdd(&cur[tgt >> 8], 1);
            pairs[pos] = (int)(((unsigned)(tgt & 255) << 17) | (unsigned)src);
        }
    } else {
        for (int e = beg + t; e < end; e += 256) {
            int src = ei[e];
            int tgt = ei[E + e];
            int pos = atomicAdd(&cur[tgt >> 8], 1);
            pairs[pos] = (int)(((unsigned)(tgt & 255) << 17) | (unsigned)src);
        }
    }
}

// K3: one block per bucket (256 nodes): LDS hist + scan -> rowptr, dinv, adj.
// Bucket bases via scan_btot_lds; segment-bounds pass folded in.
__global__ __launch_bounds__(256) void csr_bucket_kernel(
        const int* __restrict__ pairs, const int* __restrict__ btot,
        const int* __restrict__ bat, int* __restrict__ rowptr,
        int* __restrict__ adj, float* __restrict__ dinv,
        int* __restrict__ starts, int N, int E, int NB) {
    __shared__ int A[513];
    __shared__ int C[512];
    __shared__ int D[512];
    __shared__ int cur[256];
    const int b = blockIdx.x, t = threadIdx.x;
    // bounds: starts[g] = lower_bound(batch, g), starts[NG]=N
    {
        const int i = (b << 8) + t;
        if (i < N) {
            int bb = bat[i];
            int bp = (i == 0) ? -1 : bat[i - 1];
            for (int g = bp + 1; g <= bb; g++) starts[g] = i;
            if (i == N - 1)
                for (int g = bb + 1; g <= NG; g++) starts[g] = N;
        }
    }
    scan_btot_lds(btot, NB, t, A, C, D);
    const int base = A[b];
    const int end = A[b + 1];
    // per-node histogram (reuse C as h)
    C[t] = 0;
    __syncthreads();
    for (int i = base + t; i < end; i += 256)
        atomicAdd(&C[(unsigned)pairs[i] >> 17], 1);
    __syncthreads();
    const int v = C[t];
    D[t] = v;                        // reuse D as scan array
    __syncthreads();
    for (int o = 1; o < 256; o <<= 1) {
        int u = (t >= o) ? D[t - o] : 0;
        __syncthreads();
        D[t] += u;
        __syncthreads();
    }
    const int ex = D[t] - v;
    const int node = (b << 8) + t;
    if (node < N) {
        rowptr[node] = base + ex;
        dinv[node] = rsqrtf((float)v + 1.0f);
    }
    cur[t] = base + ex;
    __syncthreads();
    for (int i = base + t; i < end; i += 256) {
        unsigned p = (unsigned)pairs[i];
        int pos = atomicAdd(&cur[p >> 17], 1);
        adj[pos] = (int)(p & 0x1FFFFu);
    }
    if (b == 0 && t == 0) rowptr[N] = E;
}

// ---------------------------------------------------------------------------
// hs1[i][f] = fp8( (x[i]@W1)[f] * dinv[i] * S1 )   (32 feats -> 32 B rows)
// Row N (one past the end) is written as all-zero: the gathers clamp masked
// edge slots to index N so the loaded payload is exactly 0.0 (no VALU masking).
__global__ __launch_bounds__(256) void hs1_kernel(
        const float* __restrict__ x, const float* __restrict__ W,
        const float* __restrict__ dinv, unsigned* __restrict__ hs, int N) {
    __shared__ float Ws[32 * 32];
    __shared__ float tmp[8][32];
    for (int t = threadIdx.x; t < 1024; t += blockDim.x) Ws[t] = W[t];
    __syncthreads();
    const int tid = threadIdx.x;
    const int node = blockIdx.x * 8 + (tid >> 5);
    const int n = tid >> 5, f = tid & 31;
    if (node < N) {
        const float* xr = x + (size_t)node * 32;
        float acc = 0.f;
#pragma unroll
        for (int k = 0; k < 32; k++) acc += xr[k] * Ws[k * 32 + f];
        tmp[n][f] = acc * dinv[node] * S1F;
        if (f < 8)   // same-wave producer/consumer
            hs[(size_t)node * 8 + f] = enc4(tmp[n][4 * f], tmp[n][4 * f + 1],
                                            tmp[n][4 * f + 2], tmp[n][4 * f + 3]);
    } else if (node == N) {
        if (f < 8) hs[(size_t)N * 8 + f] = 0u;    // zero row
    }
}

// ---------------------------------------------------------------------------
// gather layer 1: 2 nodes per 32-lane group (16 nodes/block). Uniform masked
// 32-edge loop per node, both nodes' loads interleaved -> 8 adj + 8 row loads
// in flight per lane. Masked slots clamp the adj index to N (zero row).
__global__ __launch_bounds__(256) void gather1_kernel(
        const int* __restrict__ rowptr, const int* __restrict__ adj,
        const uint2* __restrict__ hs1q, const float* __restrict__ dinv,
        const float* __restrict__ b1, const float* __restrict__ W2,
        unsigned* __restrict__ hs2out, int N) {
    __shared__ float W2s[32 * 24];
    __shared__ float b1s[32];
    __shared__ float h1row[16][32];
    __shared__ float hs2t[16][32];
    const int tid = threadIdx.x;
    for (int t = tid; t < 768; t += 256) W2s[t] = W2[t];
    if (tid < 32) b1s[tid] = b1[tid];
    if (blockIdx.x == 0 && tid < 8) hs2out[(size_t)N * 8 + tid] = 0u;  // zero row for gather2

    const int g = tid >> 5;          // group 0..7
    const int l = tid & 31;
    const int f8 = l & 3;            // feature octet
    const int e8 = l >> 2;           // edge slot 0..7
    const int n0 = (blockIdx.x * 8 + g) * 2;
    const int n1 = n0 + 1;
    const bool val0 = n0 < N;
    const bool val1 = n1 < N;

    int beg0 = 0, cnt0 = 0, beg1 = 0, cnt1 = 0;
    if (val0) {
        int2 rp = *(const int2*)(rowptr + n0);       // n0 even -> 8B aligned
        beg0 = rp.x; cnt0 = rp.y - rp.x;
        if (val1) { int e2 = rowptr[n0 + 2]; beg1 = rp.y; cnt1 = e2 - rp.y; }
    }
    const int* ap0 = adj + beg0;
    const int* ap1 = adj + beg1;
    f32x2 a0[4], a1[4];
#pragma unroll
    for (int k = 0; k < 4; k++) { a0[k][0] = 0.f; a0[k][1] = 0.f; a1[k][0] = 0.f; a1[k][1] = 0.f; }

    const int jmax = max(cnt0, cnt1);
    for (int j = 0; j < jmax; j += 32) {
        const int i0 = j + e8, i1 = j + 8 + e8, i2 = j + 16 + e8, i3 = j + 24 + e8;
        // adj loads, both nodes (reads past row end land in valid workspace;
        // index clamped to zero row N)
        int sA0 = ap0[i0], sA1 = ap0[i1], sA2 = ap0[i2], sA3 = ap0[i3];
        int sB0 = ap1[i0], sB1 = ap1[i1], sB2 = ap1[i2], sB3 = ap1[i3];
        if (i0 >= cnt0) sA0 = N; if (i1 >= cnt0) sA1 = N;
        if (i2 >= cnt0) sA2 = N; if (i3 >= cnt0) sA3 = N;
        if (i0 >= cnt1) sB0 = N; if (i1 >= cnt1) sB1 = N;
        if (i2 >= cnt1) sB2 = N; if (i3 >= cnt1) sB3 = N;
        // row loads, both nodes (row N = zeros -> exact +0.0 adds)
        uint2 vA0 = hs1q[(size_t)sA0 * 4 + f8];
        uint2 vA1 = hs1q[(size_t)sA1 * 4 + f8];
        uint2 vA2 = hs1q[(size_t)sA2 * 4 + f8];
        uint2 vA3 = hs1q[(size_t)sA3 * 4 + f8];
        uint2 vB0 = hs1q[(size_t)sB0 * 4 + f8];
        uint2 vB1 = hs1q[(size_t)sB1 * 4 + f8];
        uint2 vB2 = hs1q[(size_t)sB2 * 4 + f8];
        uint2 vB3 = hs1q[(size_t)sB3 * 4 + f8];
        acc8p(vA0, a0); acc8p(vA1, a0); acc8p(vA2, a0); acc8p(vA3, a0);
        acc8p(vB0, a1); acc8p(vB1, a1); acc8p(vB2, a1); acc8p(vB3, a1);
    }
#pragma unroll
    for (int k = 0; k < 4; k++) {                // fold 8 edge slots (lane bits 2,3,4)
        float x0 = a0[k][0], x1 = a0[k][1], y0 = a1[k][0], y1 = a1[k][1];
        x0 += __shfl_xor(x0, 4); x0 += __shfl_xor(x0, 8); x0 += __shfl_xor(x0, 16);
        x1 += __shfl_xor(x1, 4); x1 += __shfl_xor(x1, 8); x1 += __shfl_xor(x1, 16);
        y0 += __shfl_xor(y0, 4); y0 += __shfl_xor(y0, 8); y0 += __shfl_xor(y0, 16);
        y1 += __shfl_xor(y1, 4); y1 += __shfl_xor(y1, 8); y1 += __shfl_xor(y1, 16);
        a0[k][0] = x0; a0[k][1] = x1; a1[k][0] = y0; a1[k][1] = y1;
    }

    __syncthreads();   // weight/bias staging visibility (all threads reach here)

    // finalize: lanes 0..3 do n0, lanes 4..7 do n1 (8 feats each)
    auto fin1 = [&](const f32x2 (&a)[4], int node, int row) {
        const int fq = l & 3;
        const float c = dinv[node] * IS1F;
        uint2 w = hs1q[(size_t)node * 4 + fq];           // self-loop term
        f32x2 s0 = __builtin_amdgcn_cvt_pk_f32_fp8((int)w.x, false);
        f32x2 s1 = __builtin_amdgcn_cvt_pk_f32_fp8((int)w.x, true);
        f32x2 s2 = __builtin_amdgcn_cvt_pk_f32_fp8((int)w.y, false);
        f32x2 s3 = __builtin_amdgcn_cvt_pk_f32_fp8((int)w.y, true);
        h1row[row][8 * fq + 0] = fmaxf(c * (a[0][0] + s0[0]) + b1s[8 * fq + 0], 0.f);
        h1row[row][8 * fq + 1] = fmaxf(c * (a[0][1] + s0[1]) + b1s[8 * fq + 1], 0.f);
        h1row[row][8 * fq + 2] = fmaxf(c * (a[1][0] + s1[0]) + b1s[8 * fq + 2], 0.f);
        h1row[row][8 * fq + 3] = fmaxf(c * (a[1][1] + s1[1]) + b1s[8 * fq + 3], 0.f);
        h1row[row][8 * fq + 4] = fmaxf(c * (a[2][0] + s2[0]) + b1s[8 * fq + 4], 0.f);
        h1row[row][8 * fq + 5] = fmaxf(c * (a[2][1] + s2[1]) + b1s[8 * fq + 5], 0.f);
        h1row[row][8 * fq + 6] = fmaxf(c * (a[3][0] + s3[0]) + b1s[8 * fq + 6], 0.f);
        h1row[row][8 * fq + 7] = fmaxf(c * (a[3][1] + s3[1]) + b1s[8 * fq + 7], 0.f);
    };
    if (l < 4) { if (val0) fin1(a0, n0, 2 * g); }
    else if (l < 8) { if (val1) fin1(a1, n1, 2 * g + 1); }

    // @W2 + fp8 stage, two serial passes (same-wave producer/consumer via LDS)
#pragma unroll
    for (int nn = 0; nn < 2; ++nn) {
        const int node = n0 + nn;
        if (node >= N) break;
        const int row = 2 * g + nn;
        const float sc = dinv[node] * S2F;
        float aa = 0.f;
        if (l < 24) {
#pragma unroll
            for (int k = 0; k < 32; k++) aa += h1row[row][k] * W2s[k * 24 + l];
        }
        hs2t[row][l] = (l < 24) ? aa * sc : 0.f;
        if (l < 8)
            hs2out[(size_t)node * 8 + l] = enc4(hs2t[row][4 * l], hs2t[row][4 * l + 1],
                                                hs2t[row][4 * l + 2], hs2t[row][4 * l + 3]);
    }
}

// gather layer 2: same 2-node structure; finalize writes h2 + fused node-MLP.
__global__ __launch_bounds__(256) void gather2_kernel(
        const int* __restrict__ rowptr, const int* __restrict__ adj,
        const uint2* __restrict__ hs2q, const float* __restrict__ dinv,
        const float* __restrict__ b2,
        const float* __restrict__ Wn1, const float* __restrict__ bn1,
        const float* __restrict__ Wn2, const float* __restrict__ bn2,
        float* __restrict__ h2out, float* __restrict__ vout, int N) {
    __shared__ float Wn1s[24 * 16];
    __shared__ float b2s[32], bn1s[16], Wn2s[16];
    __shared__ float h2row[16][32];
    const int tid = threadIdx.x;
    for (int t = tid; t < 384; t += 256) Wn1s[t] = Wn1[t];
    if (tid < 32) b2s[tid] = (tid < 24) ? b2[tid] : 0.f;
    if (tid < 16) { bn1s[tid] = bn1[tid]; Wn2s[tid] = Wn2[tid]; }

    const int g = tid >> 5;
    const int l = tid & 31;
    const int f8 = l & 3;
    const int e8 = l >> 2;
    const int n0 = (blockIdx.x * 8 + g) * 2;
    const int n1 = n0 + 1;
    const bool val0 = n0 < N;
    const bool val1 = n1 < N;

    int beg0 = 0, cnt0 = 0, beg1 = 0, cnt1 = 0;
    if (val0) {
        int2 rp = *(const int2*)(rowptr + n0);
        beg0 = rp.x; cnt0 = rp.y - rp.x;
        if (val1) { int e2 = rowptr[n0 + 2]; beg1 = rp.y; cnt1 = e2 - rp.y; }
    }
    const int* ap0 = adj + beg0;
    const int* ap1 = adj + beg1;
    f32x2 a0[4], a1[4];
#pragma unroll
    for (int k = 0; k < 4; k++) { a0[k][0] = 0.f; a0[k][1] = 0.f; a1[k][0] = 0.f; a1[k][1] = 0.f; }

    const int jmax = max(cnt0, cnt1);
    for (int j = 0; j < jmax; j += 32) {
        const int i0 = j + e8, i1 = j + 8 + e8, i2 = j + 16 + e8, i3 = j + 24 + e8;
        int sA0 = ap0[i0], sA1 = ap0[i1], sA2 = ap0[i2], sA3 = ap0[i3];
        int sB0 = ap1[i0], sB1 = ap1[i1], sB2 = ap1[i2], sB3 = ap1[i3];
        if (i0 >= cnt0) sA0 = N; if (i1 >= cnt0) sA1 = N;
        if (i2 >= cnt0) sA2 = N; if (i3 >= cnt0) sA3 = N;
        if (i0 >= cnt1) sB0 = N; if (i1 >= cnt1) sB1 = N;
        if (i2 >= cnt1) sB2 = N; if (i3 >= cnt1) sB3 = N;
        uint2 vA0 = hs2q[(size_t)sA0 * 4 + f8];
        uint2 vA1 = hs2q[(size_t)sA1 * 4 + f8];
        uint2 vA2 = hs2q[(size_t)sA2 * 4 + f8];
        uint2 vA3 = hs2q[(size_t)sA3 * 4 + f8];
        uint2 vB0 = hs2q[(size_t)sB0 * 4 + f8];
        uint2 vB1 = hs2q[(size_t)sB1 * 4 + f8];
        uint2 vB2 = hs2q[(size_t)sB2 * 4 + f8];
        uint2 vB3 = hs2q[(size_t)sB3 * 4 + f8];
        acc8p(vA0, a0); acc8p(vA1, a0); acc8p(vA2, a0); acc8p(vA3, a0);
        acc8p(vB0, a1); acc8p(vB1, a1); acc8p(vB2, a1); acc8p(vB3, a1);
    }
#pragma unroll
    for (int k = 0; k < 4; k++) {
        float x0 = a0[k][0], x1 = a0[k][1], y0 = a1[k][0], y1 = a1[k][1];
        x0 += __shfl_xor(x0, 4); x0 += __shfl_xor(x0, 8); x0 += __shfl_xor(x0, 16);
        x1 += __shfl_xor(x1, 4); x1 += __shfl_xor(x1, 8); x1 += __shfl_xor(x1, 16);
        y0 += __shfl_xor(y0, 4); y0 += __shfl_xor(y0, 8); y0 += __shfl_xor(y0, 16);
        y1 += __shfl_xor(y1, 4); y1 += __shfl_xor(y1, 8); y1 += __shfl_xor(y1, 16);
        a0[k][0] = x0; a0[k][1] = x1; a1[k][0] = y0; a1[k][1] = y1;
    }

    __syncthreads();   // weight/bias staging visibility

    auto fin2 = [&](const f32x2 (&a)[4], int node, int row) {
        const int fq = l & 3;
        const float c = dinv[node] * IS2F;
        uint2 w = hs2q[(size_t)node * 4 + fq];           // self-loop term
        f32x2 s0 = __builtin_amdgcn_cvt_pk_f32_fp8((int)w.x, false);
        f32x2 s1 = __builtin_amdgcn_cvt_pk_f32_fp8((int)w.x, true);
        f32x2 s2 = __builtin_amdgcn_cvt_pk_f32_fp8((int)w.y, false);
        f32x2 s3 = __builtin_amdgcn_cvt_pk_f32_fp8((int)w.y, true);
        // pad feats (>=24): staged 0, b2s 0 -> h2 0
        h2row[row][8 * fq + 0] = fmaxf(c * (a[0][0] + s0[0]) + b2s[8 * fq + 0], 0.f);
        h2row[row][8 * fq + 1] = fmaxf(c * (a[0][1] + s0[1]) + b2s[8 * fq + 1], 0.f);
        h2row[row][8 * fq + 2] = fmaxf(c * (a[1][0] + s1[0]) + b2s[8 * fq + 2], 0.f);
        h2row[row][8 * fq + 3] = fmaxf(c * (a[1][1] + s1[1]) + b2s[8 * fq + 3], 0.f);
        h2row[row][8 * fq + 4] = fmaxf(c * (a[2][0] + s2[0]) + b2s[8 * fq + 4], 0.f);
        h2row[row][8 * fq + 5] = fmaxf(c * (a[2][1] + s2[1]) + b2s[8 * fq + 5], 0.f);
        h2row[row][8 * fq + 6] = fmaxf(c * (a[3][0] + s3[0]) + b2s[8 * fq + 6], 0.f);
        h2row[row][8 * fq + 7] = fmaxf(c * (a[3][1] + s3[1]) + b2s[8 * fq + 7], 0.f);
    };
    if (l < 4) { if (val0) fin2(a0, n0, 2 * g); }
    else if (l < 8) { if (val1) fin2(a1, n1, 2 * g + 1); }

#pragma unroll
    for (int nn = 0; nn < 2; ++nn) {
        const int node = n0 + nn;
        if (node >= N) break;
        const int row = 2 * g + nn;
        if (l < 24) h2out[(size_t)node * 24 + l] = h2row[row][l];
        float val = 0.f;
        if (l < 16) {
            float u = bn1s[l];
#pragma unroll
            for (int k = 0; k < 24; k++) u += h2row[row][k] * Wn1s[k * 16 + l];
            val = fmaxf(u, 0.f) * Wn2s[l];
        }
        val += __shfl_down(val, 8, 16);
        val += __shfl_down(val, 4, 16);
        val += __shfl_down(val, 2, 16);
        val += __shfl_down(val, 1, 16);
        if (l == 0) vout[node] = val + bn2[0];
    }
}

// ---------------------------------------------------------------------------
// One block per graph, 1024 threads (16 waves/CU for latency hiding):
// feature-parallel segment reduction, 4x-unrolled pass B, lane-parallel heads.
__global__ __launch_bounds__(1024) void graph_kernel(
        const float* __restrict__ v, const float* __restrict__ h2,
        const int* __restrict__ starts,
        const float* __restrict__ Wg, const float* __restrict__ bg,
        const float* __restrict__ Wt, const float* __restrict__ bt,
        const float* __restrict__ Wb1p, const float* __restrict__ bb1p,
        const float* __restrict__ Wb2p, const float* __restrict__ bb2p,
        float* __restrict__ out_t, float* __restrict__ out_n,
        float* __restrict__ bbpre, int N) {
    const int g = blockIdx.x;
    const int tid = threadIdx.x;          // 0..1023
    const int lane = tid & 63;
    const int wv = tid >> 6;              // 0..15

    const int start = starts[g];
    const int end = starts[g + 1];

    __shared__ float sm[16];
    __shared__ float pH[16][24], pW[16][24], pS[16];

    // pass A: max of v over the segment (grid-stride, wave reduce)
    float m = -INFINITY;
    for (int idx = start + tid; idx < end; idx += 1024) m = fmaxf(m, v[idx]);
#pragma unroll
    for (int off = 32; off > 0; off >>= 1) m = fmaxf(m, __shfl_down(m, off, 64));
    if (lane == 0) sm[wv] = m;
    __syncthreads();
    m = sm[0];
#pragma unroll
    for (int k = 1; k < 16; k++) m = fmaxf(m, sm[k]);

    // pass B: feature-parallel accumulation, 4x unrolled (4 node-rows in flight)
    const int half = lane >> 5;
    const int slot = wv * 2 + half;       // 0..31
    const int feat = lane & 31;
    const bool fa = feat < 24;
    float hs = 0.f, ws = 0.f, se = 0.f;
    int i = start + slot;
    for (; i + 96 < end; i += 128) {
        float v0 = v[i], v1 = v[i + 32], v2 = v[i + 64], v3 = v[i + 96];
        float h0 = 0.f, h1 = 0.f, hh2 = 0.f, h3 = 0.f;
        if (fa) {
            h0 = h2[(size_t)i * 24 + feat];
            h1 = h2[(size_t)(i + 32) * 24 + feat];
            hh2 = h2[(size_t)(i + 64) * 24 + feat];
            h3 = h2[(size_t)(i + 96) * 24 + feat];
        }
        float e0 = __expf(v0 - m), e1 = __expf(v1 - m);
        float e2 = __expf(v2 - m), e3 = __expf(v3 - m);
        if (feat == 0) se += (e0 + e1) + (e2 + e3);
        hs += (h0 + h1) + (hh2 + h3);
        ws += (e0 * h0 + e1 * h1) + (e2 * hh2 + e3 * h3);
    }
    for (; i < end; i += 32) {
        float vv = v[i];
        float e = __expf(vv - m);
        if (feat == 0) se += e;
        if (fa) {
            float hv = h2[(size_t)i * 24 + feat];
            hs += hv;
            ws += e * hv;
        }
    }
    // fold the two slots within this wave (lanes differ by 32)
    hs += __shfl_xor(hs, 32, 64);
    ws += __shfl_xor(ws, 32, 64);
    se += __shfl_xor(se, 32, 64);
    if (lane < 24) { pH[wv][lane] = hs; pW[wv][lane] = ws; }
    if (lane == 0) pS[wv] = se;
    __syncthreads();
    float stot = 0.f;
#pragma unroll
    for (int k = 0; k < 16; k++) stot += pS[k];
    const float invs = (stot > 0.f) ? 1.f / stot : 0.f;

    // pass C: write normalized per-node softmax
    for (int idx = start + tid; idx < end; idx += 1024)
        out_n[idx] = __expf(v[idx] - m) * invs;

    // heads: wave 0, lane-parallel
    const float denom = fmaxf((float)(end - start), 1.0f);
    if (tid < 32) {
        // t-head: gout[o] per lane, then width-32 shuffle reduce of gout.Wt
        float a = bg[tid];
#pragma unroll
        for (int k = 0; k < 24; k++) {
            float sum_k = 0.f;
#pragma unroll
            for (int w = 0; w < 16; w++) sum_k += pH[w][k];
            a += (sum_k / denom) * Wg[k * 32 + tid];
        }
        float p0 = a * Wt[tid * 2];
        float p1 = a * Wt[tid * 2 + 1];
#pragma unroll
        for (int off = 16; off > 0; off >>= 1) {
            p0 += __shfl_down(p0, off, 32);
            p1 += __shfl_down(p1, off, 32);
        }
        if (tid == 0) {
            float t0 = p0 + bt[0], t1 = p1 + bt[1];
            float tm = fmaxf(t0, t1);
            float e0 = __expf(t0 - tm), e1 = __expf(t1 - tm);
            float ts = e0 + e1;
            out_t[g * 2 + 0] = e0 / ts;
            out_t[g * 2 + 1] = e1 / ts;
        }
    }
    if (tid < 16) {
        // b-head: u[j] per lane, then width-16 reduce for the 3 columns
        float u = bb1p[tid];
#pragma unroll
        for (int k = 0; k < 24; k++) {
            float sum_k = 0.f;
#pragma unroll
            for (int w = 0; w < 16; w++) sum_k += pW[w][k];
            u += (sum_k * invs) * Wb1p[k * 16 + tid];
        }
        u = fmaxf(u, 0.f);
        float q0 = u * Wb2p[tid * 3 + 0];
        float q1 = u * Wb2p[tid * 3 + 1];
        float q2 = u * Wb2p[tid * 3 + 2];
#pragma unroll
        for (int off = 8; off > 0; off >>= 1) {
            q0 += __shfl_down(q0, off, 16);
            q1 += __shfl_down(q1, off, 16);
            q2 += __shfl_down(q2, off, 16);
        }
        if (tid == 0) {
            bbpre[g * 3 + 0] = q0 + bb2p[0];
            bbpre[g * 3 + 1] = q1 + bb2p[1];
            bbpre[g * 3 + 2] = q2 + bb2p[2];
        }
    }
}

// column softmax over the 256 graphs (axis=0), 3 columns
__global__ __launch_bounds__(256) void bb_kernel(
        const float* __restrict__ bbpre, float* __restrict__ out_bb) {
    __shared__ float red[NG];
    int g = threadIdx.x;
#pragma unroll
    for (int c = 0; c < 3; c++) {
        float vv = bbpre[g * 3 + c];
        red[g] = vv;
        __syncthreads();
        for (int off = 128; off > 0; off >>= 1) {
            if (g < off) red[g] = fmaxf(red[g], red[g + off]);
            __syncthreads();
        }
        float m = red[0];
        __syncthreads();
        float e = __expf(vv - m);
        red[g] = e;
        __syncthreads();
        for (int off = 128; off > 0; off >>= 1) {
            if (g < off) red[g] += red[g + off];
            __syncthreads();
        }
        float ssum = red[0];
        __syncthreads();
        out_bb[g * 3 + c] = e / ssum;
    }
}

extern "C" void kernel_launch(void* const* d_in, const int* in_sizes, int n_in,
                              void* d_out, int out_size, void* d_ws, size_t ws_size,
                              hipStream_t stream) {
    const float* x   = (const float*)d_in[0];
    const int*   ei  = (const int*)d_in[1];    // [2,E] flat: row=ei[0..E), col=ei[E..2E)
    const int*   bat = (const int*)d_in[2];
    const float* W1  = (const float*)d_in[3];
    const float* b1  = (const float*)d_in[4];
    const float* W2  = (const float*)d_in[5];
    const float* b2  = (const float*)d_in[6];
    const float* Wg  = (const float*)d_in[7];
    const float* bg  = (const float*)d_in[8];
    const float* Wt  = (const float*)d_in[9];
    const float* bt  = (const float*)d_in[10];
    const float* Wn1 = (const float*)d_in[11];
    const float* bn1 = (const float*)d_in[12];
    const float* Wn2 = (const float*)d_in[13];
    const float* bn2 = (const float*)d_in[14];
    const float* Wb1 = (const float*)d_in[15];
    const float* bb1 = (const float*)d_in[16];
    const float* Wb2 = (const float*)d_in[17];
    const float* bb2 = (const float*)d_in[18];

    const int N = in_sizes[2];
    const int E = in_sizes[1] / 2;
    const int NB = (N + 255) >> 8;       // buckets of 256 nodes (<=512)
    const int M = NB * NBLK;             // blockOff matrix size

    // workspace layout (4B units):
    // persistent: rowptr[N+1] | dinv[N] | adj[E] | btot[NB] | starts[NG+1]
    // transient (aliased union):
    //   build:   blockOff[M] | pairs[E]
    //   compute: hs1 fp8 (2(N+1)) -> h2 f32 (24N) ; vbuf at +24N ;
    //            hs2 fp8 at +26N (2(N+1)) ; bbpre at +28N+4
    // NOTE: adj is followed by btot/starts (>= 31 valid words) -- gather reads
    // up to 31 entries past a row end with the index clamped to the zero row.
    auto rnd4 = [](size_t v) { return (v + 3) & ~(size_t)3; };
    size_t oRow = 0;
    size_t oDin = oRow + rnd4((size_t)N + 1);
    size_t oAdj = oDin + rnd4((size_t)N);
    size_t oTot = oAdj + rnd4((size_t)E);
    size_t oSt  = oTot + rnd4((size_t)NB);
    size_t oT   = oSt + rnd4((size_t)NG + 1);

    int*   wsi     = (int*)d_ws;
    float* wsf     = (float*)d_ws;
    int*   rowptr  = wsi + oRow;
    float* dinv    = wsf + oDin;
    int*   adj     = wsi + oAdj;
    int*   btot    = wsi + oTot;
    int*   starts  = wsi + oSt;
    int*   blkoff  = wsi + oT;
    int*   pairs   = wsi + oT + rnd4((size_t)M);
    unsigned* hs1b = (unsigned*)(wsf + oT);                  // 2(N+1) units
    float* h2      = wsf + oT;                               // reuses hs1b region after gather1
    float* vbuf    = wsf + oT + (size_t)24 * N;
    unsigned* hs2b = (unsigned*)(wsf + oT + (size_t)26 * N); // 2(N+1) units
    float* bbpre   = wsf + oT + (size_t)28 * N + 4;

    float* out_t  = (float*)d_out;          // [256,2]
    float* out_n  = out_t + 2 * NG;         // [N,1]
    float* out_bb = out_t + 2 * NG + N;     // [256,3]

    const int B = 256;

    // CSR build: hist -> scatter(+local scan) -> csr(+local scan +bounds)
    (void)hipMemsetAsync(btot, 0, (size_t)NB * sizeof(int), stream);
    hist_bucket_kernel<<<NBLK, B, 0, stream>>>(ei + E, blkoff, btot, E, NB);
    scatter_pairs_kernel<<<NBLK, B, 0, stream>>>(ei, blkoff, btot, pairs, E, NB);
    csr_bucket_kernel<<<NB, B, 0, stream>>>(pairs, btot, bat, rowptr, adj, dinv,
                                            starts, N, E, NB);

    // GCN + heads (fp8 staging rows + zero row, 2 nodes/group interleaved gathers)
    hs1_kernel<<<(N + 1 + 7) / 8, B, 0, stream>>>(x, W1, dinv, hs1b, N);
    gather1_kernel<<<(N + 15) / 16, B, 0, stream>>>(rowptr, adj, (const uint2*)hs1b,
                                                    dinv, b1, W2, hs2b, N);
    gather2_kernel<<<(N + 15) / 16, B, 0, stream>>>(rowptr, adj, (const uint2*)hs2b,
                                                    dinv, b2, Wn1, bn1, Wn2, bn2, h2, vbuf, N);
    graph_kernel<<<NG, 1024, 0, stream>>>(vbuf, h2, starts, Wg, bg, Wt, bt,
                                          Wb1, bb1, Wb2, bb2, out_t, out_n, bbpre, N);
    bb_kernel<<<1, B, 0, stream>>>(bbpre, out_bb);
}